// Round 7
// baseline (823.059 us; speedup 1.0000x reference)
//
#include <hip/hip_runtime.h>

#define HID 128

struct F4 { float v[4]; };

__device__ inline unsigned short f2bf(float f) {
    unsigned u = __float_as_uint(f);
    unsigned r = (u + 0x7fff + ((u >> 16) & 1)) >> 16;
    return (unsigned short)r;
}
__device__ inline float bf2f(unsigned short b) {
    return __uint_as_float(((unsigned)b) << 16);
}

// ================= CSR build =================
__global__ void hist_kernel(const int* __restrict__ dst, int* __restrict__ cnt, int E)
{
    int e = blockIdx.x * blockDim.x + threadIdx.x;
    if (e < E) atomicAdd(&cnt[dst[e]], 1);
}

__global__ void scan_block(const int* __restrict__ cnt, int* __restrict__ excl,
                           int* __restrict__ partials, int Nn)
{
    __shared__ int ls[256];
    int i = blockIdx.x * 256 + threadIdx.x;
    int v = (i < Nn) ? cnt[i] : 0;
    ls[threadIdx.x] = v;
    __syncthreads();
    for (int off = 1; off < 256; off <<= 1) {
        int t = (threadIdx.x >= off) ? ls[threadIdx.x - off] : 0;
        __syncthreads();
        ls[threadIdx.x] += t;
        __syncthreads();
    }
    if (i < Nn) excl[i] = ls[threadIdx.x] - v;
    if (threadIdx.x == 255) partials[blockIdx.x] = ls[255];
}

__global__ void scan_partials(int* __restrict__ partials, int nb, int* __restrict__ offsets,
                              int Nn, int E)
{
    __shared__ int ls[256];
    int t = threadIdx.x;
    int v = (t < nb) ? partials[t] : 0;
    ls[t] = v;
    __syncthreads();
    for (int off = 1; off < 256; off <<= 1) {
        int x = (t >= off) ? ls[t - off] : 0;
        __syncthreads();
        ls[t] += x;
        __syncthreads();
    }
    if (t < nb) partials[t] = ls[t] - v;
    if (t == 0) offsets[Nn] = E;
}

__global__ void scan_add(const int* __restrict__ excl, const int* __restrict__ partials,
                         int* __restrict__ offsets, int* __restrict__ cursor, int Nn)
{
    int i = blockIdx.x * 256 + threadIdx.x;
    if (i < Nn) {
        int o = excl[i] + partials[blockIdx.x];
        offsets[i] = o;
        cursor[i] = o;
    }
}

__global__ void fill_kernel(const int* __restrict__ dst, const int* __restrict__ src,
                            const float* __restrict__ ea, int* __restrict__ cursor,
                            float4* __restrict__ epack, int E)
{
    int e = blockIdx.x * blockDim.x + threadIdx.x;
    if (e < E) {
        int pos = atomicAdd(&cursor[dst[e]], 1);
        float4 p;
        p.x = __int_as_float(src[e]);
        p.y = ea[e * 3];
        p.z = ea[e * 3 + 1];
        p.w = ea[e * 3 + 2];
        epack[pos] = p;
    }
}

// ================= layer 1: CSR gather (dim 7) =================
__global__ void gather_d7(const float* __restrict__ x, const float4* __restrict__ epack,
                          const int* __restrict__ offsets,
                          const float* __restrict__ We, const float* __restrict__ be,
                          float* __restrict__ agg, int Nn)
{
    int tid = blockIdx.x * blockDim.x + threadIdx.x;
    int node = tid >> 3;
    int c = tid & 7;
    if (node >= Nn) return;
    float w0 = 0.f, w1 = 0.f, w2 = 0.f, b = 0.f;
    if (c < 7) { w0 = We[c]; w1 = We[7 + c]; w2 = We[14 + c]; b = be[c]; }
    int beg = offsets[node], end = offsets[node + 1];
    float acc = 0.f;
    for (int i = beg; i < end; ++i) {
        float4 ep = epack[i];
        int s = __float_as_int(ep.x);
        float v = b;
        v = fmaf(ep.y, w0, v);
        v = fmaf(ep.z, w1, v);
        v = fmaf(ep.w, w2, v);
        if (c < 7) v += x[s * 7 + c];
        acc += fmaxf(v, 0.f);
    }
    if (c < 7) agg[node * 7 + c] = acc;
}

// ================= layers 2/3: gather, 4x unrolled, writes h+agg =================
__global__ void gather_d128(const unsigned short* __restrict__ h16,
                            const float4* __restrict__ epack,
                            const int* __restrict__ offsets,
                            const float* __restrict__ We, const float* __restrict__ be,
                            const float* __restrict__ hprev,
                            float* __restrict__ agg, int Nn)
{
    int node = blockIdx.x * (blockDim.x >> 6) + (threadIdx.x >> 6);
    if (node >= Nn) return;
    int lane = threadIdx.x & 63;
    int beg = offsets[node], end = offsets[node + 1];
    const float2* W2 = (const float2*)We;
    float2 w0 = W2[lane];
    float2 w1 = W2[64 + lane];
    float2 w2 = W2[128 + lane];
    float2 bb = ((const float2*)be)[lane];
    float accx = 0.f, accy = 0.f;

    int i = beg;
    for (; i + 4 <= end; i += 4) {
        float4 e0 = epack[i], e1 = epack[i + 1], e2 = epack[i + 2], e3 = epack[i + 3];
        ushort2 p0 = ((const ushort2*)(h16 + (size_t)__float_as_int(e0.x) * HID))[lane];
        ushort2 p1 = ((const ushort2*)(h16 + (size_t)__float_as_int(e1.x) * HID))[lane];
        ushort2 p2 = ((const ushort2*)(h16 + (size_t)__float_as_int(e2.x) * HID))[lane];
        ushort2 p3 = ((const ushort2*)(h16 + (size_t)__float_as_int(e3.x) * HID))[lane];
        float vx, vy;
        vx = bb.x + bf2f(p0.x);
        vx = fmaf(e0.y, w0.x, vx); vx = fmaf(e0.z, w1.x, vx); vx = fmaf(e0.w, w2.x, vx);
        vy = bb.y + bf2f(p0.y);
        vy = fmaf(e0.y, w0.y, vy); vy = fmaf(e0.z, w1.y, vy); vy = fmaf(e0.w, w2.y, vy);
        accx += fmaxf(vx, 0.f); accy += fmaxf(vy, 0.f);
        vx = bb.x + bf2f(p1.x);
        vx = fmaf(e1.y, w0.x, vx); vx = fmaf(e1.z, w1.x, vx); vx = fmaf(e1.w, w2.x, vx);
        vy = bb.y + bf2f(p1.y);
        vy = fmaf(e1.y, w0.y, vy); vy = fmaf(e1.z, w1.y, vy); vy = fmaf(e1.w, w2.y, vy);
        accx += fmaxf(vx, 0.f); accy += fmaxf(vy, 0.f);
        vx = bb.x + bf2f(p2.x);
        vx = fmaf(e2.y, w0.x, vx); vx = fmaf(e2.z, w1.x, vx); vx = fmaf(e2.w, w2.x, vx);
        vy = bb.y + bf2f(p2.y);
        vy = fmaf(e2.y, w0.y, vy); vy = fmaf(e2.z, w1.y, vy); vy = fmaf(e2.w, w2.y, vy);
        accx += fmaxf(vx, 0.f); accy += fmaxf(vy, 0.f);
        vx = bb.x + bf2f(p3.x);
        vx = fmaf(e3.y, w0.x, vx); vx = fmaf(e3.z, w1.x, vx); vx = fmaf(e3.w, w2.x, vx);
        vy = bb.y + bf2f(p3.y);
        vy = fmaf(e3.y, w0.y, vy); vy = fmaf(e3.z, w1.y, vy); vy = fmaf(e3.w, w2.y, vy);
        accx += fmaxf(vx, 0.f); accy += fmaxf(vy, 0.f);
    }
    for (; i < end; ++i) {
        float4 ep = epack[i];
        ushort2 hp = ((const ushort2*)(h16 + (size_t)__float_as_int(ep.x) * HID))[lane];
        float vx = bb.x + bf2f(hp.x);
        vx = fmaf(ep.y, w0.x, vx); vx = fmaf(ep.z, w1.x, vx); vx = fmaf(ep.w, w2.x, vx);
        float vy = bb.y + bf2f(hp.y);
        vy = fmaf(ep.y, w0.y, vy); vy = fmaf(ep.z, w1.y, vy); vy = fmaf(ep.w, w2.y, vy);
        accx += fmaxf(vx, 0.f);
        accy += fmaxf(vy, 0.f);
    }
    float2 hv = ((const float2*)(hprev + (size_t)node * HID))[lane];
    float2 outv = {accx + hv.x, accy + hv.y};
    ((float2*)(agg + (size_t)node * HID))[lane] = outv;
}

// ===== tiled fp32 GEMM, 32-node tiles, padded LDS, col-split waves =====
// block: 256 thr = 4 waves; wave w covers cols [32w,32w+32); thread: nodes {ng, ng+16} x 8 cols
#define LDSROW 132
template <bool RELU, bool STATS>
__global__ __launch_bounds__(256, 4) void gemm128_t32(const float* __restrict__ A,
                                                      const float* __restrict__ W,
                                                      const float* __restrict__ bias,
                                                      float* __restrict__ C,
                                                      float* __restrict__ bnsums, int N)
{
    __shared__ float As[32 * LDSROW];
    __shared__ float sls[128], slq[128];
    int t = threadIdx.x;
    int nb = blockIdx.x * 32;
    int rows = N - nb < 32 ? (N - nb) : 32;
    {
        const float4* A4 = (const float4*)(A + (size_t)nb * HID);
        int limit4 = 32 * rows;
#pragma unroll
        for (int i = 0; i < 4; ++i) {
            int g = t + i * 256;
            float4 v = {0.f, 0.f, 0.f, 0.f};
            if (g < limit4) v = A4[g];
            int row = g >> 5, col = g & 31;
            *(float4*)(As + row * LDSROW + col * 4) = v;
        }
        if (STATS && t < 128) { sls[t] = 0.f; slq[t] = 0.f; }
    }
    __syncthreads();

    int wave = t >> 6;
    int lane = t & 63;
    int c8 = lane & 3;          // col sub-group
    int ng = lane >> 2;         // node group 0..15
    int colbase = wave * 32 + c8 * 8;
    const float4* W4 = (const float4*)W;
    float4 acc[2][2];
    {
        const float4* Bb = (const float4*)bias;
        float4 b0 = Bb[colbase >> 2], b1 = Bb[(colbase >> 2) + 1];
        acc[0][0] = b0; acc[0][1] = b1; acc[1][0] = b0; acc[1][1] = b1;
    }
    const float* As0 = As + ng * LDSROW;
    const float* As1 = As + (ng + 16) * LDSROW;
#pragma unroll 8
    for (int k = 0; k < HID; k += 4) {
        F4 a0 = *(const F4*)(As0 + k);
        F4 a1 = *(const F4*)(As1 + k);
#pragma unroll
        for (int kk = 0; kk < 4; ++kk) {
            float4 w0 = W4[(k + kk) * 32 + (colbase >> 2)];
            float4 w1 = W4[(k + kk) * 32 + (colbase >> 2) + 1];
            float av0 = a0.v[kk], av1 = a1.v[kk];
            acc[0][0].x = fmaf(av0, w0.x, acc[0][0].x);
            acc[0][0].y = fmaf(av0, w0.y, acc[0][0].y);
            acc[0][0].z = fmaf(av0, w0.z, acc[0][0].z);
            acc[0][0].w = fmaf(av0, w0.w, acc[0][0].w);
            acc[0][1].x = fmaf(av0, w1.x, acc[0][1].x);
            acc[0][1].y = fmaf(av0, w1.y, acc[0][1].y);
            acc[0][1].z = fmaf(av0, w1.z, acc[0][1].z);
            acc[0][1].w = fmaf(av0, w1.w, acc[0][1].w);
            acc[1][0].x = fmaf(av1, w0.x, acc[1][0].x);
            acc[1][0].y = fmaf(av1, w0.y, acc[1][0].y);
            acc[1][0].z = fmaf(av1, w0.z, acc[1][0].z);
            acc[1][0].w = fmaf(av1, w0.w, acc[1][0].w);
            acc[1][1].x = fmaf(av1, w1.x, acc[1][1].x);
            acc[1][1].y = fmaf(av1, w1.y, acc[1][1].y);
            acc[1][1].z = fmaf(av1, w1.z, acc[1][1].z);
            acc[1][1].w = fmaf(av1, w1.w, acc[1][1].w);
        }
    }
    float s8[8], q8[8];
    if (STATS) {
#pragma unroll
        for (int u = 0; u < 8; ++u) { s8[u] = 0.f; q8[u] = 0.f; }
    }
#pragma unroll
    for (int j = 0; j < 2; ++j) {
        int n = nb + ng + j * 16;
        if (n < N) {
            float4 o0 = acc[j][0], o1 = acc[j][1];
            if (RELU) {
                o0.x = fmaxf(o0.x, 0.f); o0.y = fmaxf(o0.y, 0.f);
                o0.z = fmaxf(o0.z, 0.f); o0.w = fmaxf(o0.w, 0.f);
                o1.x = fmaxf(o1.x, 0.f); o1.y = fmaxf(o1.y, 0.f);
                o1.z = fmaxf(o1.z, 0.f); o1.w = fmaxf(o1.w, 0.f);
            }
            if (STATS) {
                const float* p0 = (const float*)&o0;
                const float* p1 = (const float*)&o1;
#pragma unroll
                for (int u = 0; u < 4; ++u) {
                    s8[u] += p0[u];     q8[u] = fmaf(p0[u], p0[u], q8[u]);
                    s8[4 + u] += p1[u]; q8[4 + u] = fmaf(p1[u], p1[u], q8[4 + u]);
                }
            }
            float4* Cp = (float4*)(C + (size_t)n * HID) + (colbase >> 2);
            Cp[0] = o0;
            Cp[1] = o1;
        }
    }
    if (STATS) {
        // reduce across the 16 node-group lanes (stride 4,8,16,32)
#pragma unroll
        for (int off = 4; off < 64; off <<= 1) {
#pragma unroll
            for (int u = 0; u < 8; ++u) {
                s8[u] += __shfl_down(s8[u], off);
                q8[u] += __shfl_down(q8[u], off);
            }
        }
        if (ng == 0) {
#pragma unroll
            for (int u = 0; u < 8; ++u) {
                atomicAdd(&sls[colbase + u], s8[u]);
                atomicAdd(&slq[colbase + u], q8[u]);
            }
        }
        __syncthreads();
        if (t < 128) {
            atomicAdd(&bnsums[t], sls[t]);
            atomicAdd(&bnsums[128 + t], slq[t]);
        }
    }
}

// ================= small GEMM for layer-1 (K=7) =================
template <int K, bool HASADD, bool RELU>
__global__ void mlp_gemm(const float* __restrict__ A, const float* __restrict__ A2,
                         const float* __restrict__ W, const float* __restrict__ bias,
                         float* __restrict__ C, int N)
{
    long long gid = (long long)blockIdx.x * blockDim.x + threadIdx.x;
    long long total = (long long)N * 32;
    if (gid >= total) return;
    int n = (int)(gid >> 5);
    int c4 = (int)(gid & 31);
    const float4* W4 = (const float4*)W;
    const float4* B4 = (const float4*)bias;
    float4 acc = B4[c4];
    const float* arow = A + (long long)n * K;
    const float* arow2 = A2 ? (A2 + (long long)n * K) : nullptr;
#pragma unroll 4
    for (int k = 0; k < K; ++k) {
        float a = arow[k];
        if (HASADD) a += arow2[k];
        float4 w = W4[k * 32 + c4];
        acc.x = fmaf(a, w.x, acc.x);
        acc.y = fmaf(a, w.y, acc.y);
        acc.z = fmaf(a, w.z, acc.z);
        acc.w = fmaf(a, w.w, acc.w);
    }
    if (RELU) {
        acc.x = fmaxf(acc.x, 0.f); acc.y = fmaxf(acc.y, 0.f);
        acc.z = fmaxf(acc.z, 0.f); acc.w = fmaxf(acc.w, 0.f);
    }
    ((float4*)C)[gid] = acc;
}

// ================= BN =================
__global__ void bn_finalize(const float* __restrict__ sums, const float* __restrict__ g,
                            const float* __restrict__ bt, float* __restrict__ ab, int N)
{
    int c = threadIdx.x;
    if (c < 128) {
        float inv = 1.f / (float)N;
        float mu = sums[c] * inv;
        float var = sums[128 + c] * inv - mu * mu;
        float rs = rsqrtf(fmaxf(var, 0.f) + 1e-5f);
        float a = g[c] * rs;
        ab[c] = a;
        ab[128 + c] = bt[c] - a * mu;
    }
}

template <bool W16>
__global__ void bn_apply_relu(const float* __restrict__ h, const float* __restrict__ ab,
                              float* __restrict__ out, unsigned short* __restrict__ h16,
                              long long total)
{
    long long i = ((long long)blockIdx.x * blockDim.x + threadIdx.x) * 2;
    if (i >= total) return;
    int c = (int)(i & 127);
    float2 hv = *(const float2*)(h + i);
    float v0 = fmaxf(fmaf(hv.x, ab[c], ab[128 + c]), 0.f);
    float v1 = fmaxf(fmaf(hv.y, ab[c + 1], ab[129 + c]), 0.f);
    float2 ov = {v0, v1};
    *(float2*)(out + i) = ov;
    if (W16) {
        unsigned pair = (unsigned)f2bf(v0) | ((unsigned)f2bf(v1) << 16);
        *(unsigned*)(h16 + i) = pair;
    }
}

// ================= fused layer-3 BN-apply + mean-pool scatter =================
__global__ void bn_pool(const float* __restrict__ agg, const float* __restrict__ ab,
                        const int* __restrict__ batch,
                        float* __restrict__ pools, float* __restrict__ cnt, int N)
{
    long long i = (long long)blockIdx.x * blockDim.x + threadIdx.x;
    long long total = (long long)N * HID;
    if (i >= total) return;
    int n = (int)(i >> 7);
    int c = (int)(i & 127);
    int g = batch[n];
    float v = fmaxf(fmaf(agg[i], ab[c], ab[128 + c]), 0.f);
    atomicAdd(&pools[(long long)g * HID + c], v);
    if (c == 0) atomicAdd(&cnt[g], 1.f);
}

__global__ void head_kernel(const float* __restrict__ pools, const float* __restrict__ cnt,
                            const float* __restrict__ Wf1, const float* __restrict__ bf1,
                            const float* __restrict__ Wf2, const float* __restrict__ bf2,
                            float* __restrict__ out, int G)
{
    int g = blockIdx.x;
    int t = threadIdx.x;
    __shared__ float p[128];
    float inv = 1.f / fmaxf(cnt[g], 1.f);
    p[t] = pools[g * 128 + t] * inv;
    p[t + 64] = pools[g * 128 + t + 64] * inv;
    __syncthreads();
    float o = bf1[t];
#pragma unroll 8
    for (int k = 0; k < 128; ++k) o = fmaf(p[k], Wf1[k * 64 + t], o);
    o = fmaxf(o, 0.f);
    float prod = o * Wf2[t];
#pragma unroll
    for (int off = 32; off > 0; off >>= 1) prod += __shfl_down(prod, off);
    if (t == 0) out[g] = prod + bf2[0];
}

extern "C" void kernel_launch(void* const* d_in, const int* in_sizes, int n_in,
                              void* d_out, int out_size, void* d_ws, size_t ws_size,
                              hipStream_t stream)
{
    const float* x     = (const float*)d_in[0];
    const float* ea    = (const float*)d_in[1];
    const int*   eidx  = (const int*)d_in[2];
    const int*   batch = (const int*)d_in[3];
    const float* We1 = (const float*)d_in[4];  const float* be1 = (const float*)d_in[5];
    const float* W11 = (const float*)d_in[6];  const float* b11 = (const float*)d_in[7];
    const float* W12 = (const float*)d_in[8];  const float* b12 = (const float*)d_in[9];
    const float* g1  = (const float*)d_in[10]; const float* bt1 = (const float*)d_in[11];
    const float* We2 = (const float*)d_in[12]; const float* be2 = (const float*)d_in[13];
    const float* W21 = (const float*)d_in[14]; const float* b21 = (const float*)d_in[15];
    const float* W22 = (const float*)d_in[16]; const float* b22 = (const float*)d_in[17];
    const float* g2  = (const float*)d_in[18]; const float* bt2 = (const float*)d_in[19];
    const float* We3 = (const float*)d_in[20]; const float* be3 = (const float*)d_in[21];
    const float* W31 = (const float*)d_in[22]; const float* b31 = (const float*)d_in[23];
    const float* W32 = (const float*)d_in[24]; const float* b32 = (const float*)d_in[25];
    const float* g3  = (const float*)d_in[26]; const float* bt3 = (const float*)d_in[27];
    const float* Wf1 = (const float*)d_in[28]; const float* bf1 = (const float*)d_in[29];
    const float* Wf2 = (const float*)d_in[30]; const float* bf2 = (const float*)d_in[31];

    const int N = in_sizes[0] / 7;
    const int E = in_sizes[1] / 3;
    const int G = out_size;
    const int* src = eidx;
    const int* dst = eidx + E;

    float* ws = (float*)d_ws;
    float* buf_h   = ws;                          // N*128
    float* buf_agg = buf_h + (size_t)N * HID;     // N*128
    float* buf_t   = buf_agg + (size_t)N * HID;   // N*128
    float* bnsums  = buf_t + (size_t)N * HID;     // 256
    float* bnab    = bnsums + 256;                // 256
    float* pools   = bnab + 256;                  // G*128
    float* cntp    = pools + (size_t)G * HID;     // G
    float4* epack  = (float4*)(cntp + G);         // E float4
    unsigned short* h16 = (unsigned short*)(epack + E);  // N*128 bf16
    int*   icnt    = (int*)(h16 + (size_t)N * HID); // N
    int*   ioffs   = icnt + N;                    // N+1
    int*   icur    = ioffs + N + 1;               // N
    int*   ipart   = icur + N;                    // 256
    int*   iexcl   = ipart + 256;                 // N

    const long long NH = (long long)N * HID;
    const int blk = 256;
    const unsigned grid_nh2  = (unsigned)((NH / 2 + blk - 1) / blk);
    const unsigned grid_nh   = (unsigned)((NH + blk - 1) / blk);
    const unsigned grid_gemm = (unsigned)(((long long)N * 32 + blk - 1) / blk);
    const unsigned grid_t32  = (unsigned)((N + 31) / 32);
    const unsigned grid_E    = (unsigned)((E + blk - 1) / blk);
    const unsigned nb_scan   = (unsigned)((N + 255) / 256);
    const unsigned grid_gather = (unsigned)((N + 3) / 4);
    const unsigned grid_gat7 = (unsigned)(((long long)N * 8 + blk - 1) / blk);

    // ---------- build CSR with packed edges ----------
    hipMemsetAsync(icnt, 0, (size_t)N * sizeof(int), stream);
    hist_kernel<<<grid_E, blk, 0, stream>>>(dst, icnt, E);
    scan_block<<<nb_scan, 256, 0, stream>>>(icnt, iexcl, ipart, N);
    scan_partials<<<1, 256, 0, stream>>>(ipart, nb_scan, ioffs, N, E);
    scan_add<<<nb_scan, 256, 0, stream>>>(iexcl, ipart, ioffs, icur, N);
    fill_kernel<<<grid_E, blk, 0, stream>>>(dst, src, ea, icur, epack, E);

    // ---------- layer 1 ----------
    hipMemsetAsync(bnsums, 0, 256 * sizeof(float), stream);
    gather_d7<<<grid_gat7, blk, 0, stream>>>(x, epack, ioffs, We1, be1, buf_agg, N);
    mlp_gemm<7, true, true><<<grid_gemm, blk, 0, stream>>>(x, buf_agg, W11, b11, buf_t, N);
    gemm128_t32<false, true><<<grid_t32, 256, 0, stream>>>(buf_t, W12, b12, buf_agg, bnsums, N);
    bn_finalize<<<1, 128, 0, stream>>>(bnsums, g1, bt1, bnab, N);
    bn_apply_relu<true><<<grid_nh2, blk, 0, stream>>>(buf_agg, bnab, buf_h, h16, NH);

    // ---------- layer 2 ----------
    hipMemsetAsync(bnsums, 0, 256 * sizeof(float), stream);
    gather_d128<<<grid_gather, 256, 0, stream>>>(h16, epack, ioffs, We2, be2, buf_h, buf_agg, N);
    gemm128_t32<true, false><<<grid_t32, 256, 0, stream>>>(buf_agg, W21, b21, buf_t, nullptr, N);
    gemm128_t32<false, true><<<grid_t32, 256, 0, stream>>>(buf_t, W22, b22, buf_agg, bnsums, N);
    bn_finalize<<<1, 128, 0, stream>>>(bnsums, g2, bt2, bnab, N);
    bn_apply_relu<true><<<grid_nh2, blk, 0, stream>>>(buf_agg, bnab, buf_h, h16, NH);

    // ---------- layer 3 ----------
    hipMemsetAsync(bnsums, 0, 256 * sizeof(float), stream);
    gather_d128<<<grid_gather, 256, 0, stream>>>(h16, epack, ioffs, We3, be3, buf_h, buf_agg, N);
    gemm128_t32<true, false><<<grid_t32, 256, 0, stream>>>(buf_agg, W31, b31, buf_t, nullptr, N);
    gemm128_t32<false, true><<<grid_t32, 256, 0, stream>>>(buf_t, W32, b32, buf_agg, bnsums, N);
    bn_finalize<<<1, 128, 0, stream>>>(bnsums, g3, bt3, bnab, N);

    // ---------- fused BN-apply + pool, then head ----------
    hipMemsetAsync(pools, 0, ((size_t)G * HID + G) * sizeof(float), stream);
    bn_pool<<<grid_nh, blk, 0, stream>>>(buf_agg, bnab, batch, pools, cntp, N);
    head_kernel<<<G, 64, 0, stream>>>(pools, cntp, Wf1, bf1, Wf2, bf2, (float*)d_out, G);
}

// Round 8
// 669.474 us; speedup vs baseline: 1.2294x; 1.2294x over previous
//
#include <hip/hip_runtime.h>

#define HID 128

typedef __attribute__((ext_vector_type(8))) short bf16x8;
typedef __attribute__((ext_vector_type(4))) float f32x4;

__device__ inline unsigned short f2bf(float f) {
    unsigned u = __float_as_uint(f);
    unsigned r = (u + 0x7fff + ((u >> 16) & 1)) >> 16;
    return (unsigned short)r;
}
__device__ inline float bf2f(unsigned short b) {
    return __uint_as_float(((unsigned)b) << 16);
}

// ================= CSR build =================
__global__ void hist_kernel(const int* __restrict__ dst, int* __restrict__ cnt, int E)
{
    int e = blockIdx.x * blockDim.x + threadIdx.x;
    if (e < E) atomicAdd(&cnt[dst[e]], 1);
}

__global__ void scan_block(const int* __restrict__ cnt, int* __restrict__ excl,
                           int* __restrict__ partials, int Nn)
{
    __shared__ int ls[256];
    int i = blockIdx.x * 256 + threadIdx.x;
    int v = (i < Nn) ? cnt[i] : 0;
    ls[threadIdx.x] = v;
    __syncthreads();
    for (int off = 1; off < 256; off <<= 1) {
        int t = (threadIdx.x >= off) ? ls[threadIdx.x - off] : 0;
        __syncthreads();
        ls[threadIdx.x] += t;
        __syncthreads();
    }
    if (i < Nn) excl[i] = ls[threadIdx.x] - v;
    if (threadIdx.x == 255) partials[blockIdx.x] = ls[255];
}

__global__ void scan_partials(int* __restrict__ partials, int nb, int* __restrict__ offsets,
                              int Nn, int E)
{
    __shared__ int ls[256];
    int t = threadIdx.x;
    int v = (t < nb) ? partials[t] : 0;
    ls[t] = v;
    __syncthreads();
    for (int off = 1; off < 256; off <<= 1) {
        int x = (t >= off) ? ls[t - off] : 0;
        __syncthreads();
        ls[t] += x;
        __syncthreads();
    }
    if (t < nb) partials[t] = ls[t] - v;
    if (t == 0) offsets[Nn] = E;
}

__global__ void scan_add(const int* __restrict__ excl, const int* __restrict__ partials,
                         int* __restrict__ offsets, int* __restrict__ cursor, int Nn)
{
    int i = blockIdx.x * 256 + threadIdx.x;
    if (i < Nn) {
        int o = excl[i] + partials[blockIdx.x];
        offsets[i] = o;
        cursor[i] = o;
    }
}

__global__ void fill_kernel(const int* __restrict__ dst, const int* __restrict__ src,
                            const float* __restrict__ ea, int* __restrict__ cursor,
                            float4* __restrict__ epack, int E)
{
    int e = blockIdx.x * blockDim.x + threadIdx.x;
    if (e < E) {
        int pos = atomicAdd(&cursor[dst[e]], 1);
        float4 p;
        p.x = __int_as_float(src[e]);
        p.y = ea[e * 3];
        p.z = ea[e * 3 + 1];
        p.w = ea[e * 3 + 2];
        epack[pos] = p;
    }
}

// ======= W precompute: transpose + hi/lo bf16 split: Wt[n][k] from W[k][n] =======
__global__ void wsplit(const float* __restrict__ W, unsigned short* __restrict__ wh,
                       unsigned short* __restrict__ wl)
{
    int idx = blockIdx.x * 256 + threadIdx.x;  // 64 blocks x 256 = 16384
    int n = idx >> 7, k = idx & 127;
    float w = W[k * 128 + n];
    unsigned short h = (unsigned short)(__float_as_uint(w) >> 16);  // truncate
    float lo = w - bf2f(h);
    unsigned short l = (unsigned short)(__float_as_uint(lo) >> 16);
    wh[idx] = h;
    wl[idx] = l;
}

// ================= layer 1: CSR gather (dim 7) =================
__global__ void gather_d7(const float* __restrict__ x, const float4* __restrict__ epack,
                          const int* __restrict__ offsets,
                          const float* __restrict__ We, const float* __restrict__ be,
                          float* __restrict__ agg, int Nn)
{
    int tid = blockIdx.x * blockDim.x + threadIdx.x;
    int node = tid >> 3;
    int c = tid & 7;
    if (node >= Nn) return;
    float w0 = 0.f, w1 = 0.f, w2 = 0.f, b = 0.f;
    if (c < 7) { w0 = We[c]; w1 = We[7 + c]; w2 = We[14 + c]; b = be[c]; }
    int beg = offsets[node], end = offsets[node + 1];
    float acc = 0.f;
    for (int i = beg; i < end; ++i) {
        float4 ep = epack[i];
        int s = __float_as_int(ep.x);
        float v = b;
        v = fmaf(ep.y, w0, v);
        v = fmaf(ep.z, w1, v);
        v = fmaf(ep.w, w2, v);
        if (c < 7) v += x[s * 7 + c];
        acc += fmaxf(v, 0.f);
    }
    if (c < 7) agg[node * 7 + c] = acc;
}

// ================= layers 2/3: gather, 4x unrolled, writes h+agg =================
__global__ void gather_d128(const unsigned short* __restrict__ h16,
                            const float4* __restrict__ epack,
                            const int* __restrict__ offsets,
                            const float* __restrict__ We, const float* __restrict__ be,
                            const float* __restrict__ hprev,
                            float* __restrict__ agg, int Nn)
{
    int node = blockIdx.x * (blockDim.x >> 6) + (threadIdx.x >> 6);
    if (node >= Nn) return;
    int lane = threadIdx.x & 63;
    int beg = offsets[node], end = offsets[node + 1];
    const float2* W2 = (const float2*)We;
    float2 w0 = W2[lane];
    float2 w1 = W2[64 + lane];
    float2 w2 = W2[128 + lane];
    float2 bb = ((const float2*)be)[lane];
    float accx = 0.f, accy = 0.f;

    int i = beg;
    for (; i + 4 <= end; i += 4) {
        float4 e0 = epack[i], e1 = epack[i + 1], e2 = epack[i + 2], e3 = epack[i + 3];
        ushort2 p0 = ((const ushort2*)(h16 + (size_t)__float_as_int(e0.x) * HID))[lane];
        ushort2 p1 = ((const ushort2*)(h16 + (size_t)__float_as_int(e1.x) * HID))[lane];
        ushort2 p2 = ((const ushort2*)(h16 + (size_t)__float_as_int(e2.x) * HID))[lane];
        ushort2 p3 = ((const ushort2*)(h16 + (size_t)__float_as_int(e3.x) * HID))[lane];
        float vx, vy;
        vx = bb.x + bf2f(p0.x);
        vx = fmaf(e0.y, w0.x, vx); vx = fmaf(e0.z, w1.x, vx); vx = fmaf(e0.w, w2.x, vx);
        vy = bb.y + bf2f(p0.y);
        vy = fmaf(e0.y, w0.y, vy); vy = fmaf(e0.z, w1.y, vy); vy = fmaf(e0.w, w2.y, vy);
        accx += fmaxf(vx, 0.f); accy += fmaxf(vy, 0.f);
        vx = bb.x + bf2f(p1.x);
        vx = fmaf(e1.y, w0.x, vx); vx = fmaf(e1.z, w1.x, vx); vx = fmaf(e1.w, w2.x, vx);
        vy = bb.y + bf2f(p1.y);
        vy = fmaf(e1.y, w0.y, vy); vy = fmaf(e1.z, w1.y, vy); vy = fmaf(e1.w, w2.y, vy);
        accx += fmaxf(vx, 0.f); accy += fmaxf(vy, 0.f);
        vx = bb.x + bf2f(p2.x);
        vx = fmaf(e2.y, w0.x, vx); vx = fmaf(e2.z, w1.x, vx); vx = fmaf(e2.w, w2.x, vx);
        vy = bb.y + bf2f(p2.y);
        vy = fmaf(e2.y, w0.y, vy); vy = fmaf(e2.z, w1.y, vy); vy = fmaf(e2.w, w2.y, vy);
        accx += fmaxf(vx, 0.f); accy += fmaxf(vy, 0.f);
        vx = bb.x + bf2f(p3.x);
        vx = fmaf(e3.y, w0.x, vx); vx = fmaf(e3.z, w1.x, vx); vx = fmaf(e3.w, w2.x, vx);
        vy = bb.y + bf2f(p3.y);
        vy = fmaf(e3.y, w0.y, vy); vy = fmaf(e3.z, w1.y, vy); vy = fmaf(e3.w, w2.y, vy);
        accx += fmaxf(vx, 0.f); accy += fmaxf(vy, 0.f);
    }
    for (; i < end; ++i) {
        float4 ep = epack[i];
        ushort2 hp = ((const ushort2*)(h16 + (size_t)__float_as_int(ep.x) * HID))[lane];
        float vx = bb.x + bf2f(hp.x);
        vx = fmaf(ep.y, w0.x, vx); vx = fmaf(ep.z, w1.x, vx); vx = fmaf(ep.w, w2.x, vx);
        float vy = bb.y + bf2f(hp.y);
        vy = fmaf(ep.y, w0.y, vy); vy = fmaf(ep.z, w1.y, vy); vy = fmaf(ep.w, w2.y, vy);
        accx += fmaxf(vx, 0.f);
        accy += fmaxf(vy, 0.f);
    }
    float2 hv = ((const float2*)(hprev + (size_t)node * HID))[lane];
    float2 outv = {accx + hv.x, accy + hv.y};
    ((float2*)(agg + (size_t)node * HID))[lane] = outv;
}

// ===== MFMA GEMM: C[N,128] = op(A[N,128] @ W) via bf16 hi/lo split (~fp32 exact) =====
// block 256 = 4 waves; wave handles 16 rows x 128 cols = 8 C-tiles of 16x16
template <bool RELU, bool STATS>
__global__ __launch_bounds__(256) void gemm128_mfma(
    const float* __restrict__ A,
    const unsigned short* __restrict__ Wh,  // Wt[n][k] hi bf16
    const unsigned short* __restrict__ Wl,  // Wt[n][k] lo bf16
    const float* __restrict__ bias,
    float* __restrict__ C,
    float* __restrict__ bnsums, int N)
{
    __shared__ float sls[128], slq[128];
    int t = threadIdx.x;
    int wave = t >> 6, lane = t & 63;
    int q = lane >> 4, li = lane & 15;
    int node0 = blockIdx.x * 64 + wave * 16;
    if (STATS) {
        if (t < 128) { sls[t] = 0.f; slq[t] = 0.f; }
        __syncthreads();
    }

    f32x4 acc[8];
#pragma unroll
    for (int ct = 0; ct < 8; ++ct) {
        float b = bias[ct * 16 + li];
        acc[ct][0] = b; acc[ct][1] = b; acc[ct][2] = b; acc[ct][3] = b;
    }

    int arow = node0 + li;                 // a-frag row for this lane
    const float* Ap = A + (size_t)arow * HID;
    bool arow_ok = arow < N;

#pragma unroll
    for (int kb = 0; kb < 4; ++kb) {
        int k0 = kb * 32 + q * 8;          // this lane's 8 k-values
        float4 av0 = {0.f, 0.f, 0.f, 0.f}, av1 = {0.f, 0.f, 0.f, 0.f};
        if (arow_ok) {
            av0 = *(const float4*)(Ap + k0);
            av1 = *(const float4*)(Ap + k0 + 4);
        }
        float af[8] = {av0.x, av0.y, av0.z, av0.w, av1.x, av1.y, av1.z, av1.w};
        bf16x8 ah, al;
#pragma unroll
        for (int j = 0; j < 8; ++j) {
            unsigned short h = (unsigned short)(__float_as_uint(af[j]) >> 16);
            float lo = af[j] - bf2f(h);
            ah[j] = (short)h;
            al[j] = (short)(__float_as_uint(lo) >> 16);
        }
#pragma unroll
        for (int ct = 0; ct < 8; ++ct) {
            size_t woff = (size_t)(ct * 16 + li) * HID + k0;
            bf16x8 bh = *(const bf16x8*)(Wh + woff);
            bf16x8 bl = *(const bf16x8*)(Wl + woff);
            acc[ct] = __builtin_amdgcn_mfma_f32_16x16x32_bf16(ah, bh, acc[ct], 0, 0, 0);
            acc[ct] = __builtin_amdgcn_mfma_f32_16x16x32_bf16(ah, bl, acc[ct], 0, 0, 0);
            acc[ct] = __builtin_amdgcn_mfma_f32_16x16x32_bf16(al, bh, acc[ct], 0, 0, 0);
        }
    }

    // epilogue: D layout col=li, row=q*4+r
#pragma unroll
    for (int ct = 0; ct < 8; ++ct) {
        float sv = 0.f, qv = 0.f;
#pragma unroll
        for (int r = 0; r < 4; ++r) {
            int n = node0 + q * 4 + r;
            float v = acc[ct][r];
            if (RELU) v = fmaxf(v, 0.f);
            if (n < N) {
                C[(size_t)n * HID + ct * 16 + li] = v;
                if (STATS) { sv += v; qv = fmaf(v, v, qv); }
            }
        }
        if (STATS) {
            sv += __shfl_down(sv, 16); sv += __shfl_down(sv, 32);
            qv += __shfl_down(qv, 16); qv += __shfl_down(qv, 32);
            if (q == 0) {
                atomicAdd(&sls[ct * 16 + li], sv);
                atomicAdd(&slq[ct * 16 + li], qv);
            }
        }
    }
    if (STATS) {
        __syncthreads();
        if (t < 128) {
            atomicAdd(&bnsums[t], sls[t]);
            atomicAdd(&bnsums[128 + t], slq[t]);
        }
    }
}

// ================= small GEMM for layer-1 (K=7) =================
template <int K, bool HASADD, bool RELU>
__global__ void mlp_gemm(const float* __restrict__ A, const float* __restrict__ A2,
                         const float* __restrict__ W, const float* __restrict__ bias,
                         float* __restrict__ C, int N)
{
    long long gid = (long long)blockIdx.x * blockDim.x + threadIdx.x;
    long long total = (long long)N * 32;
    if (gid >= total) return;
    int n = (int)(gid >> 5);
    int c4 = (int)(gid & 31);
    const float4* W4 = (const float4*)W;
    const float4* B4 = (const float4*)bias;
    float4 acc = B4[c4];
    const float* arow = A + (long long)n * K;
    const float* arow2 = A2 ? (A2 + (long long)n * K) : nullptr;
#pragma unroll 4
    for (int k = 0; k < K; ++k) {
        float a = arow[k];
        if (HASADD) a += arow2[k];
        float4 w = W4[k * 32 + c4];
        acc.x = fmaf(a, w.x, acc.x);
        acc.y = fmaf(a, w.y, acc.y);
        acc.z = fmaf(a, w.z, acc.z);
        acc.w = fmaf(a, w.w, acc.w);
    }
    if (RELU) {
        acc.x = fmaxf(acc.x, 0.f); acc.y = fmaxf(acc.y, 0.f);
        acc.z = fmaxf(acc.z, 0.f); acc.w = fmaxf(acc.w, 0.f);
    }
    ((float4*)C)[gid] = acc;
}

// ================= BN =================
__global__ void bn_finalize(const float* __restrict__ sums, const float* __restrict__ g,
                            const float* __restrict__ bt, float* __restrict__ ab, int N)
{
    int c = threadIdx.x;
    if (c < 128) {
        float inv = 1.f / (float)N;
        float mu = sums[c] * inv;
        float var = sums[128 + c] * inv - mu * mu;
        float rs = rsqrtf(fmaxf(var, 0.f) + 1e-5f);
        float a = g[c] * rs;
        ab[c] = a;
        ab[128 + c] = bt[c] - a * mu;
    }
}

template <bool W16>
__global__ void bn_apply_relu(const float* __restrict__ h, const float* __restrict__ ab,
                              float* __restrict__ out, unsigned short* __restrict__ h16,
                              long long total)
{
    long long i = ((long long)blockIdx.x * blockDim.x + threadIdx.x) * 2;
    if (i >= total) return;
    int c = (int)(i & 127);
    float2 hv = *(const float2*)(h + i);
    float v0 = fmaxf(fmaf(hv.x, ab[c], ab[128 + c]), 0.f);
    float v1 = fmaxf(fmaf(hv.y, ab[c + 1], ab[129 + c]), 0.f);
    float2 ov = {v0, v1};
    *(float2*)(out + i) = ov;
    if (W16) {
        unsigned pair = (unsigned)f2bf(v0) | ((unsigned)f2bf(v1) << 16);
        *(unsigned*)(h16 + i) = pair;
    }
}

// ================= fused layer-3 BN-apply + mean-pool scatter =================
__global__ void bn_pool(const float* __restrict__ agg, const float* __restrict__ ab,
                        const int* __restrict__ batch,
                        float* __restrict__ pools, float* __restrict__ cnt, int N)
{
    long long i = (long long)blockIdx.x * blockDim.x + threadIdx.x;
    long long total = (long long)N * HID;
    if (i >= total) return;
    int n = (int)(i >> 7);
    int c = (int)(i & 127);
    int g = batch[n];
    float v = fmaxf(fmaf(agg[i], ab[c], ab[128 + c]), 0.f);
    atomicAdd(&pools[(long long)g * HID + c], v);
    if (c == 0) atomicAdd(&cnt[g], 1.f);
}

__global__ void head_kernel(const float* __restrict__ pools, const float* __restrict__ cnt,
                            const float* __restrict__ Wf1, const float* __restrict__ bf1,
                            const float* __restrict__ Wf2, const float* __restrict__ bf2,
                            float* __restrict__ out, int G)
{
    int g = blockIdx.x;
    int t = threadIdx.x;
    __shared__ float p[128];
    float inv = 1.f / fmaxf(cnt[g], 1.f);
    p[t] = pools[g * 128 + t] * inv;
    p[t + 64] = pools[g * 128 + t + 64] * inv;
    __syncthreads();
    float o = bf1[t];
#pragma unroll 8
    for (int k = 0; k < 128; ++k) o = fmaf(p[k], Wf1[k * 64 + t], o);
    o = fmaxf(o, 0.f);
    float prod = o * Wf2[t];
#pragma unroll
    for (int off = 32; off > 0; off >>= 1) prod += __shfl_down(prod, off);
    if (t == 0) out[g] = prod + bf2[0];
}

extern "C" void kernel_launch(void* const* d_in, const int* in_sizes, int n_in,
                              void* d_out, int out_size, void* d_ws, size_t ws_size,
                              hipStream_t stream)
{
    const float* x     = (const float*)d_in[0];
    const float* ea    = (const float*)d_in[1];
    const int*   eidx  = (const int*)d_in[2];
    const int*   batch = (const int*)d_in[3];
    const float* We1 = (const float*)d_in[4];  const float* be1 = (const float*)d_in[5];
    const float* W11 = (const float*)d_in[6];  const float* b11 = (const float*)d_in[7];
    const float* W12 = (const float*)d_in[8];  const float* b12 = (const float*)d_in[9];
    const float* g1  = (const float*)d_in[10]; const float* bt1 = (const float*)d_in[11];
    const float* We2 = (const float*)d_in[12]; const float* be2 = (const float*)d_in[13];
    const float* W21 = (const float*)d_in[14]; const float* b21 = (const float*)d_in[15];
    const float* W22 = (const float*)d_in[16]; const float* b22 = (const float*)d_in[17];
    const float* g2  = (const float*)d_in[18]; const float* bt2 = (const float*)d_in[19];
    const float* We3 = (const float*)d_in[20]; const float* be3 = (const float*)d_in[21];
    const float* W31 = (const float*)d_in[22]; const float* b31 = (const float*)d_in[23];
    const float* W32 = (const float*)d_in[24]; const float* b32 = (const float*)d_in[25];
    const float* g3  = (const float*)d_in[26]; const float* bt3 = (const float*)d_in[27];
    const float* Wf1 = (const float*)d_in[28]; const float* bf1 = (const float*)d_in[29];
    const float* Wf2 = (const float*)d_in[30]; const float* bf2 = (const float*)d_in[31];

    const int N = in_sizes[0] / 7;
    const int E = in_sizes[1] / 3;
    const int G = out_size;
    const int* src = eidx;
    const int* dst = eidx + E;

    float* ws = (float*)d_ws;
    float* buf_h   = ws;                          // N*128
    float* buf_agg = buf_h + (size_t)N * HID;     // N*128
    float* buf_t   = buf_agg + (size_t)N * HID;   // N*128
    float* bnsums  = buf_t + (size_t)N * HID;     // 256
    float* bnab    = bnsums + 256;                // 256
    float* pools   = bnab + 256;                  // G*128
    float* cntp    = pools + (size_t)G * HID;     // G
    float4* epack  = (float4*)(cntp + G);         // E float4
    unsigned short* h16 = (unsigned short*)(epack + E);  // N*128 bf16
    int*   icnt    = (int*)(h16 + (size_t)N * HID); // N
    int*   ioffs   = icnt + N;                    // N+1
    int*   icur    = ioffs + N + 1;               // N
    int*   ipart   = icur + N;                    // 256
    int*   iexcl   = ipart + 256;                 // N
    unsigned short* wt = (unsigned short*)(iexcl + N);  // 5 x 2 x 16384
    unsigned short* w12h = wt;            unsigned short* w12l = wt + 16384;
    unsigned short* w21h = wt + 32768;    unsigned short* w21l = wt + 49152;
    unsigned short* w22h = wt + 65536;    unsigned short* w22l = wt + 81920;
    unsigned short* w31h = wt + 98304;    unsigned short* w31l = wt + 114688;
    unsigned short* w32h = wt + 131072;   unsigned short* w32l = wt + 147456;

    const long long NH = (long long)N * HID;
    const int blk = 256;
    const unsigned grid_nh2  = (unsigned)((NH / 2 + blk - 1) / blk);
    const unsigned grid_nh   = (unsigned)((NH + blk - 1) / blk);
    const unsigned grid_gemm = (unsigned)(((long long)N * 32 + blk - 1) / blk);
    const unsigned grid_mfma = (unsigned)((N + 63) / 64);
    const unsigned grid_E    = (unsigned)((E + blk - 1) / blk);
    const unsigned nb_scan   = (unsigned)((N + 255) / 256);
    const unsigned grid_gather = (unsigned)((N + 3) / 4);
    const unsigned grid_gat7 = (unsigned)(((long long)N * 8 + blk - 1) / blk);

    // ---------- W splits (once) ----------
    wsplit<<<64, 256, 0, stream>>>(W12, w12h, w12l);
    wsplit<<<64, 256, 0, stream>>>(W21, w21h, w21l);
    wsplit<<<64, 256, 0, stream>>>(W22, w22h, w22l);
    wsplit<<<64, 256, 0, stream>>>(W31, w31h, w31l);
    wsplit<<<64, 256, 0, stream>>>(W32, w32h, w32l);

    // ---------- build CSR with packed edges ----------
    hipMemsetAsync(icnt, 0, (size_t)N * sizeof(int), stream);
    hist_kernel<<<grid_E, blk, 0, stream>>>(dst, icnt, E);
    scan_block<<<nb_scan, 256, 0, stream>>>(icnt, iexcl, ipart, N);
    scan_partials<<<1, 256, 0, stream>>>(ipart, nb_scan, ioffs, N, E);
    scan_add<<<nb_scan, 256, 0, stream>>>(iexcl, ipart, ioffs, icur, N);
    fill_kernel<<<grid_E, blk, 0, stream>>>(dst, src, ea, icur, epack, E);

    // ---------- layer 1 ----------
    hipMemsetAsync(bnsums, 0, 256 * sizeof(float), stream);
    gather_d7<<<grid_gat7, blk, 0, stream>>>(x, epack, ioffs, We1, be1, buf_agg, N);
    mlp_gemm<7, true, true><<<grid_gemm, blk, 0, stream>>>(x, buf_agg, W11, b11, buf_t, N);
    gemm128_mfma<false, true><<<grid_mfma, 256, 0, stream>>>(buf_t, w12h, w12l, b12, buf_agg, bnsums, N);
    bn_finalize<<<1, 128, 0, stream>>>(bnsums, g1, bt1, bnab, N);
    bn_apply_relu<true><<<grid_nh2, blk, 0, stream>>>(buf_agg, bnab, buf_h, h16, NH);

    // ---------- layer 2 ----------
    hipMemsetAsync(bnsums, 0, 256 * sizeof(float), stream);
    gather_d128<<<grid_gather, 256, 0, stream>>>(h16, epack, ioffs, We2, be2, buf_h, buf_agg, N);
    gemm128_mfma<true, false><<<grid_mfma, 256, 0, stream>>>(buf_agg, w21h, w21l, b21, buf_t, nullptr, N);
    gemm128_mfma<false, true><<<grid_mfma, 256, 0, stream>>>(buf_t, w22h, w22l, b22, buf_agg, bnsums, N);
    bn_finalize<<<1, 128, 0, stream>>>(bnsums, g2, bt2, bnab, N);
    bn_apply_relu<true><<<grid_nh2, blk, 0, stream>>>(buf_agg, bnab, buf_h, h16, NH);

    // ---------- layer 3 ----------
    hipMemsetAsync(bnsums, 0, 256 * sizeof(float), stream);
    gather_d128<<<grid_gather, 256, 0, stream>>>(h16, epack, ioffs, We3, be3, buf_h, buf_agg, N);
    gemm128_mfma<true, false><<<grid_mfma, 256, 0, stream>>>(buf_agg, w31h, w31l, b31, buf_t, nullptr, N);
    gemm128_mfma<false, true><<<grid_mfma, 256, 0, stream>>>(buf_t, w32h, w32l, b32, buf_agg, bnsums, N);
    bn_finalize<<<1, 128, 0, stream>>>(bnsums, g3, bt3, bnab, N);

    // ---------- fused BN-apply + pool, then head ----------
    hipMemsetAsync(pools, 0, ((size_t)G * HID + G) * sizeof(float), stream);
    bn_pool<<<grid_nh, blk, 0, stream>>>(buf_agg, bnab, batch, pools, cntp, N);
    head_kernel<<<G, 64, 0, stream>>>(pools, cntp, Wf1, bf1, Wf2, bf2, (float*)d_out, G);
}

// Round 10
// 635.207 us; speedup vs baseline: 1.2957x; 1.0539x over previous
//
#include <hip/hip_runtime.h>

#define HID 128

typedef __attribute__((ext_vector_type(8))) short bf16x8;
typedef __attribute__((ext_vector_type(4))) float f32x4;

__device__ inline unsigned short f2bf(float f) {
    unsigned u = __float_as_uint(f);
    unsigned r = (u + 0x7fff + ((u >> 16) & 1)) >> 16;
    return (unsigned short)r;
}
__device__ inline float bf2f(unsigned short b) {
    return __uint_as_float(((unsigned)b) << 16);
}
// split v into trunc-bf16 hi (low 16 bits) + trunc-bf16 lo (high 16 bits)
__device__ inline unsigned packhl(float v) {
    unsigned h = __float_as_uint(v) >> 16;
    float lo = v - __uint_as_float(h << 16);
    unsigned l = __float_as_uint(lo) >> 16;
    return h | (l << 16);
}

// ================= CSR build =================
__global__ void hist_kernel(const int* __restrict__ dst, int* __restrict__ cnt, int E)
{
    int e = blockIdx.x * blockDim.x + threadIdx.x;
    if (e < E) atomicAdd(&cnt[dst[e]], 1);
}

__global__ void scan_block(const int* __restrict__ cnt, int* __restrict__ excl,
                           int* __restrict__ partials, int Nn)
{
    __shared__ int ls[256];
    int i = blockIdx.x * 256 + threadIdx.x;
    int v = (i < Nn) ? cnt[i] : 0;
    ls[threadIdx.x] = v;
    __syncthreads();
    for (int off = 1; off < 256; off <<= 1) {
        int t = (threadIdx.x >= off) ? ls[threadIdx.x - off] : 0;
        __syncthreads();
        ls[threadIdx.x] += t;
        __syncthreads();
    }
    if (i < Nn) excl[i] = ls[threadIdx.x] - v;
    if (threadIdx.x == 255) partials[blockIdx.x] = ls[255];
}

__global__ void scan_partials(int* __restrict__ partials, int nb, int* __restrict__ offsets,
                              int Nn, int E)
{
    __shared__ int ls[256];
    int t = threadIdx.x;
    int v = (t < nb) ? partials[t] : 0;
    ls[t] = v;
    __syncthreads();
    for (int off = 1; off < 256; off <<= 1) {
        int x = (t >= off) ? ls[t - off] : 0;
        __syncthreads();
        ls[t] += x;
        __syncthreads();
    }
    if (t < nb) partials[t] = ls[t] - v;
    if (t == 0) offsets[Nn] = E;
}

__global__ void scan_add(const int* __restrict__ excl, const int* __restrict__ partials,
                         int* __restrict__ offsets, int* __restrict__ cursor, int Nn)
{
    int i = blockIdx.x * 256 + threadIdx.x;
    if (i < Nn) {
        int o = excl[i] + partials[blockIdx.x];
        offsets[i] = o;
        cursor[i] = o;
    }
}

__global__ void fill_kernel(const int* __restrict__ dst, const int* __restrict__ src,
                            const float* __restrict__ ea, int* __restrict__ cursor,
                            float4* __restrict__ epack, int E)
{
    int e = blockIdx.x * blockDim.x + threadIdx.x;
    if (e < E) {
        int pos = atomicAdd(&cursor[dst[e]], 1);
        float4 p;
        p.x = __int_as_float(src[e]);
        p.y = ea[e * 3];
        p.z = ea[e * 3 + 1];
        p.w = ea[e * 3 + 2];
        epack[pos] = p;
    }
}

// ======= W precompute: transpose + hi/lo bf16 split: Wt[n][k] from W[k][n] =======
__global__ void wsplit(const float* __restrict__ W, unsigned short* __restrict__ wh,
                       unsigned short* __restrict__ wl)
{
    int idx = blockIdx.x * 256 + threadIdx.x;
    int n = idx >> 7, k = idx & 127;
    float w = W[k * 128 + n];
    unsigned short h = (unsigned short)(__float_as_uint(w) >> 16);
    float lo = w - bf2f(h);
    unsigned short l = (unsigned short)(__float_as_uint(lo) >> 16);
    wh[idx] = h;
    wl[idx] = l;
}

// ================= layer 1: CSR gather (dim 7) =================
__global__ void gather_d7(const float* __restrict__ x, const float4* __restrict__ epack,
                          const int* __restrict__ offsets,
                          const float* __restrict__ We, const float* __restrict__ be,
                          float* __restrict__ agg, int Nn)
{
    int tid = blockIdx.x * blockDim.x + threadIdx.x;
    int node = tid >> 3;
    int c = tid & 7;
    if (node >= Nn) return;
    float w0 = 0.f, w1 = 0.f, w2 = 0.f, b = 0.f;
    if (c < 7) { w0 = We[c]; w1 = We[7 + c]; w2 = We[14 + c]; b = be[c]; }
    int beg = offsets[node], end = offsets[node + 1];
    float acc = 0.f;
    for (int i = beg; i < end; ++i) {
        float4 ep = epack[i];
        int s = __float_as_int(ep.x);
        float v = b;
        v = fmaf(ep.y, w0, v);
        v = fmaf(ep.z, w1, v);
        v = fmaf(ep.w, w2, v);
        if (c < 7) v += x[s * 7 + c];
        acc += fmaxf(v, 0.f);
    }
    if (c < 7) agg[node * 7 + c] = acc;
}

// ================= layers 2/3: gather, 4x unrolled, writes h+agg =================
__global__ void gather_d128(const unsigned short* __restrict__ h16,
                            const float4* __restrict__ epack,
                            const int* __restrict__ offsets,
                            const float* __restrict__ We, const float* __restrict__ be,
                            const float* __restrict__ hprev,
                            float* __restrict__ agg, int Nn)
{
    int node = blockIdx.x * (blockDim.x >> 6) + (threadIdx.x >> 6);
    if (node >= Nn) return;
    int lane = threadIdx.x & 63;
    int beg = offsets[node], end = offsets[node + 1];
    const float2* W2 = (const float2*)We;
    float2 w0 = W2[lane];
    float2 w1 = W2[64 + lane];
    float2 w2 = W2[128 + lane];
    float2 bb = ((const float2*)be)[lane];
    float accx = 0.f, accy = 0.f;

    int i = beg;
    for (; i + 4 <= end; i += 4) {
        float4 e0 = epack[i], e1 = epack[i + 1], e2 = epack[i + 2], e3 = epack[i + 3];
        ushort2 p0 = ((const ushort2*)(h16 + (size_t)__float_as_int(e0.x) * HID))[lane];
        ushort2 p1 = ((const ushort2*)(h16 + (size_t)__float_as_int(e1.x) * HID))[lane];
        ushort2 p2 = ((const ushort2*)(h16 + (size_t)__float_as_int(e2.x) * HID))[lane];
        ushort2 p3 = ((const ushort2*)(h16 + (size_t)__float_as_int(e3.x) * HID))[lane];
        float vx, vy;
        vx = bb.x + bf2f(p0.x);
        vx = fmaf(e0.y, w0.x, vx); vx = fmaf(e0.z, w1.x, vx); vx = fmaf(e0.w, w2.x, vx);
        vy = bb.y + bf2f(p0.y);
        vy = fmaf(e0.y, w0.y, vy); vy = fmaf(e0.z, w1.y, vy); vy = fmaf(e0.w, w2.y, vy);
        accx += fmaxf(vx, 0.f); accy += fmaxf(vy, 0.f);
        vx = bb.x + bf2f(p1.x);
        vx = fmaf(e1.y, w0.x, vx); vx = fmaf(e1.z, w1.x, vx); vx = fmaf(e1.w, w2.x, vx);
        vy = bb.y + bf2f(p1.y);
        vy = fmaf(e1.y, w0.y, vy); vy = fmaf(e1.z, w1.y, vy); vy = fmaf(e1.w, w2.y, vy);
        accx += fmaxf(vx, 0.f); accy += fmaxf(vy, 0.f);
        vx = bb.x + bf2f(p2.x);
        vx = fmaf(e2.y, w0.x, vx); vx = fmaf(e2.z, w1.x, vx); vx = fmaf(e2.w, w2.x, vx);
        vy = bb.y + bf2f(p2.y);
        vy = fmaf(e2.y, w0.y, vy); vy = fmaf(e2.z, w1.y, vy); vy = fmaf(e2.w, w2.y, vy);
        accx += fmaxf(vx, 0.f); accy += fmaxf(vy, 0.f);
        vx = bb.x + bf2f(p3.x);
        vx = fmaf(e3.y, w0.x, vx); vx = fmaf(e3.z, w1.x, vx); vx = fmaf(e3.w, w2.x, vx);
        vy = bb.y + bf2f(p3.y);
        vy = fmaf(e3.y, w0.y, vy); vy = fmaf(e3.z, w1.y, vy); vy = fmaf(e3.w, w2.y, vy);
        accx += fmaxf(vx, 0.f); accy += fmaxf(vy, 0.f);
    }
    for (; i < end; ++i) {
        float4 ep = epack[i];
        ushort2 hp = ((const ushort2*)(h16 + (size_t)__float_as_int(ep.x) * HID))[lane];
        float vx = bb.x + bf2f(hp.x);
        vx = fmaf(ep.y, w0.x, vx); vx = fmaf(ep.z, w1.x, vx); vx = fmaf(ep.w, w2.x, vx);
        float vy = bb.y + bf2f(hp.y);
        vy = fmaf(ep.y, w0.y, vy); vy = fmaf(ep.z, w1.y, vy); vy = fmaf(ep.w, w2.y, vy);
        accx += fmaxf(vx, 0.f);
        accy += fmaxf(vy, 0.f);
    }
    float2 hv = ((const float2*)(hprev + (size_t)node * HID))[lane];
    float2 outv = {accx + hv.x, accy + hv.y};
    ((float2*)(agg + (size_t)node * HID))[lane] = outv;
}

// ===== phase 2 of the fused MLP: T (packed hi/lo in LDS) @ W2 + epilogue =====
// NOTE: Ts deliberately NOT __restrict__, and a __syncthreads() fences the
// phase-1 ds_writes from the phase-2 ds_reads (compiler may otherwise hoist
// the reads above the writes under noalias scopes -> stale LDS).
template <bool RELU, bool STATS>
__device__ __forceinline__ void phase2_epilogue(
    const unsigned* Ts,
    const unsigned short* __restrict__ Wh, const unsigned short* __restrict__ Wl,
    const float* __restrict__ bias, float* __restrict__ C,
    float* __restrict__ bnsums, float* sls, float* slq,
    int node0, int wave, int q, int li, int t, int N)
{
    __syncthreads();   // fence: all phase-1 LDS writes visible before reads
    f32x4 acc[8];
#pragma unroll
    for (int ct = 0; ct < 8; ++ct) {
        float b = bias[ct * 16 + li];
        acc[ct][0] = b; acc[ct][1] = b; acc[ct][2] = b; acc[ct][3] = b;
    }
    const unsigned* Tp = Ts + (wave * 16 + li) * 132;
#pragma unroll
    for (int kb = 0; kb < 4; ++kb) {
        int k0 = kb * 32 + q * 8;
        uint4 pa = *(const uint4*)(Tp + k0);
        uint4 pb = *(const uint4*)(Tp + k0 + 4);
        unsigned pv[8] = {pa.x, pa.y, pa.z, pa.w, pb.x, pb.y, pb.z, pb.w};
        bf16x8 ah, al;
#pragma unroll
        for (int j = 0; j < 8; ++j) {
            ah[j] = (short)(pv[j] & 0xffffu);
            al[j] = (short)(pv[j] >> 16);
        }
        bf16x8 bh[8], bl[8];
#pragma unroll
        for (int ct = 0; ct < 8; ++ct) {
            size_t woff = (size_t)(ct * 16 + li) * HID + k0;
            bh[ct] = *(const bf16x8*)(Wh + woff);
            bl[ct] = *(const bf16x8*)(Wl + woff);
        }
#pragma unroll
        for (int ct = 0; ct < 8; ++ct) {
            acc[ct] = __builtin_amdgcn_mfma_f32_16x16x32_bf16(ah, bh[ct], acc[ct], 0, 0, 0);
            acc[ct] = __builtin_amdgcn_mfma_f32_16x16x32_bf16(ah, bl[ct], acc[ct], 0, 0, 0);
            acc[ct] = __builtin_amdgcn_mfma_f32_16x16x32_bf16(al, bh[ct], acc[ct], 0, 0, 0);
        }
    }
#pragma unroll
    for (int ct = 0; ct < 8; ++ct) {
        float sv = 0.f, qv = 0.f;
#pragma unroll
        for (int r = 0; r < 4; ++r) {
            int n = node0 + q * 4 + r;
            float v = acc[ct][r];
            if (RELU) v = fmaxf(v, 0.f);
            if (n < N) {
                C[(size_t)n * HID + ct * 16 + li] = v;
                if (STATS) { sv += v; qv = fmaf(v, v, qv); }
            }
        }
        if (STATS) {
            sv += __shfl_down(sv, 16); sv += __shfl_down(sv, 32);
            qv += __shfl_down(qv, 16); qv += __shfl_down(qv, 32);
            if (q == 0) {
                atomicAdd(&sls[ct * 16 + li], sv);
                atomicAdd(&slq[ct * 16 + li], qv);
            }
        }
    }
    if (STATS) {
        __syncthreads();
        if (t < 128) {
            atomicAdd(&bnsums[t], sls[t]);
            atomicAdd(&bnsums[128 + t], slq[t]);
        }
    }
}

// ===== fused MLP for layers 2/3: C = Lin2(relu(Lin1(A))) with fused BN stats =====
template <bool RELU, bool STATS>
__global__ __launch_bounds__(256) void mlp128_fused(
    const float* __restrict__ A,
    const unsigned short* __restrict__ W1h, const unsigned short* __restrict__ W1l,
    const float* __restrict__ b1,
    const unsigned short* __restrict__ W2h, const unsigned short* __restrict__ W2l,
    const float* __restrict__ b2,
    float* __restrict__ C, float* __restrict__ bnsums, int N)
{
    __shared__ unsigned Ts[64 * 132];
    __shared__ float sls[128], slq[128];
    int t = threadIdx.x;
    int wave = t >> 6, lane = t & 63;
    int q = lane >> 4, li = lane & 15;
    int node0 = blockIdx.x * 64 + wave * 16;
    if (STATS) {
        if (t < 128) { sls[t] = 0.f; slq[t] = 0.f; }
    }

    f32x4 acc[8];
#pragma unroll
    for (int ct = 0; ct < 8; ++ct) {
        float b = b1[ct * 16 + li];
        acc[ct][0] = b; acc[ct][1] = b; acc[ct][2] = b; acc[ct][3] = b;
    }
    int arow = node0 + li;
    const float* Ap = A + (size_t)arow * HID;
    bool ok = arow < N;
#pragma unroll
    for (int kb = 0; kb < 4; ++kb) {
        int k0 = kb * 32 + q * 8;
        float4 av0 = {0.f, 0.f, 0.f, 0.f}, av1 = {0.f, 0.f, 0.f, 0.f};
        if (ok) {
            av0 = *(const float4*)(Ap + k0);
            av1 = *(const float4*)(Ap + k0 + 4);
        }
        float af[8] = {av0.x, av0.y, av0.z, av0.w, av1.x, av1.y, av1.z, av1.w};
        bf16x8 ah, al;
#pragma unroll
        for (int j = 0; j < 8; ++j) {
            unsigned short h = (unsigned short)(__float_as_uint(af[j]) >> 16);
            float lo = af[j] - bf2f(h);
            ah[j] = (short)h;
            al[j] = (short)(__float_as_uint(lo) >> 16);
        }
        bf16x8 bh[8], bl[8];
#pragma unroll
        for (int ct = 0; ct < 8; ++ct) {
            size_t woff = (size_t)(ct * 16 + li) * HID + k0;
            bh[ct] = *(const bf16x8*)(W1h + woff);
            bl[ct] = *(const bf16x8*)(W1l + woff);
        }
#pragma unroll
        for (int ct = 0; ct < 8; ++ct) {
            acc[ct] = __builtin_amdgcn_mfma_f32_16x16x32_bf16(ah, bh[ct], acc[ct], 0, 0, 0);
            acc[ct] = __builtin_amdgcn_mfma_f32_16x16x32_bf16(ah, bl[ct], acc[ct], 0, 0, 0);
            acc[ct] = __builtin_amdgcn_mfma_f32_16x16x32_bf16(al, bh[ct], acc[ct], 0, 0, 0);
        }
    }
    // relu + hi/lo pack into LDS
#pragma unroll
    for (int ct = 0; ct < 8; ++ct) {
#pragma unroll
        for (int r = 0; r < 4; ++r) {
            float v = fmaxf(acc[ct][r], 0.f);
            Ts[(wave * 16 + q * 4 + r) * 132 + ct * 16 + li] = packhl(v);
        }
    }
    phase2_epilogue<RELU, STATS>(Ts, W2h, W2l, b2, C, bnsums, sls, slq, node0, wave, q, li, t, N);
}

// ===== fused MLP for layer 1: phase-1 K=7 fp32 vector, phase-2 MFMA =====
template <bool RELU, bool STATS>
__global__ __launch_bounds__(256) void mlp1_fused(
    const float* __restrict__ x, const float* __restrict__ agg,
    const float* __restrict__ W1, const float* __restrict__ b1,     // [7][128]
    const unsigned short* __restrict__ W2h, const unsigned short* __restrict__ W2l,
    const float* __restrict__ b2,
    float* __restrict__ C, float* __restrict__ bnsums, int N)
{
    __shared__ unsigned Ts[64 * 132];
    __shared__ float sls[128], slq[128];
    int t = threadIdx.x;
    int wave = t >> 6, lane = t & 63;
    int q = lane >> 4, li = lane & 15;
    int node0 = blockIdx.x * 64 + wave * 16;
    if (STATS) {
        if (t < 128) { sls[t] = 0.f; slq[t] = 0.f; }
    }

    int row = node0 + li;
    bool ok = row < N;
    float xa[7];
#pragma unroll
    for (int k = 0; k < 7; ++k) xa[k] = ok ? (x[row * 7 + k] + agg[row * 7 + k]) : 0.f;
    const float4* W14 = (const float4*)W1;
    const float4* b14 = (const float4*)b1;
    unsigned* Trow = Ts + (wave * 16 + li) * 132 + q * 32;
#pragma unroll
    for (int c4 = 0; c4 < 8; ++c4) {
        float4 v = b14[q * 8 + c4];
#pragma unroll
        for (int k = 0; k < 7; ++k) {
            float4 w = W14[k * 32 + q * 8 + c4];
            v.x = fmaf(xa[k], w.x, v.x);
            v.y = fmaf(xa[k], w.y, v.y);
            v.z = fmaf(xa[k], w.z, v.z);
            v.w = fmaf(xa[k], w.w, v.w);
        }
        uint4 pk;
        pk.x = packhl(fmaxf(v.x, 0.f));
        pk.y = packhl(fmaxf(v.y, 0.f));
        pk.z = packhl(fmaxf(v.z, 0.f));
        pk.w = packhl(fmaxf(v.w, 0.f));
        *(uint4*)(Trow + c4 * 4) = pk;
    }
    phase2_epilogue<RELU, STATS>(Ts, W2h, W2l, b2, C, bnsums, sls, slq, node0, wave, q, li, t, N);
}

// ================= BN =================
__global__ void bn_finalize(const float* __restrict__ sums, const float* __restrict__ g,
                            const float* __restrict__ bt, float* __restrict__ ab, int N)
{
    int c = threadIdx.x;
    if (c < 128) {
        float inv = 1.f / (float)N;
        float mu = sums[c] * inv;
        float var = sums[128 + c] * inv - mu * mu;
        float rs = rsqrtf(fmaxf(var, 0.f) + 1e-5f);
        float a = g[c] * rs;
        ab[c] = a;
        ab[128 + c] = bt[c] - a * mu;
    }
}

template <bool W16>
__global__ void bn_apply_relu(const float* __restrict__ h, const float* __restrict__ ab,
                              float* __restrict__ out, unsigned short* __restrict__ h16,
                              long long total)
{
    long long i = ((long long)blockIdx.x * blockDim.x + threadIdx.x) * 2;
    if (i >= total) return;
    int c = (int)(i & 127);
    float2 hv = *(const float2*)(h + i);
    float v0 = fmaxf(fmaf(hv.x, ab[c], ab[128 + c]), 0.f);
    float v1 = fmaxf(fmaf(hv.y, ab[c + 1], ab[129 + c]), 0.f);
    float2 ov = {v0, v1};
    *(float2*)(out + i) = ov;
    if (W16) {
        unsigned pair = (unsigned)f2bf(v0) | ((unsigned)f2bf(v1) << 16);
        *(unsigned*)(h16 + i) = pair;
    }
}

// ================= fused layer-3 BN-apply + mean-pool scatter =================
__global__ void bn_pool(const float* __restrict__ agg, const float* __restrict__ ab,
                        const int* __restrict__ batch,
                        float* __restrict__ pools, float* __restrict__ cnt, int N)
{
    long long i = (long long)blockIdx.x * blockDim.x + threadIdx.x;
    long long total = (long long)N * HID;
    if (i >= total) return;
    int n = (int)(i >> 7);
    int c = (int)(i & 127);
    int g = batch[n];
    float v = fmaxf(fmaf(agg[i], ab[c], ab[128 + c]), 0.f);
    atomicAdd(&pools[(long long)g * HID + c], v);
    if (c == 0) atomicAdd(&cnt[g], 1.f);
}

__global__ void head_kernel(const float* __restrict__ pools, const float* __restrict__ cnt,
                            const float* __restrict__ Wf1, const float* __restrict__ bf1,
                            const float* __restrict__ Wf2, const float* __restrict__ bf2,
                            float* __restrict__ out, int G)
{
    int g = blockIdx.x;
    int t = threadIdx.x;
    __shared__ float p[128];
    float inv = 1.f / fmaxf(cnt[g], 1.f);
    p[t] = pools[g * 128 + t] * inv;
    p[t + 64] = pools[g * 128 + t + 64] * inv;
    __syncthreads();
    float o = bf1[t];
#pragma unroll 8
    for (int k = 0; k < 128; ++k) o = fmaf(p[k], Wf1[k * 64 + t], o);
    o = fmaxf(o, 0.f);
    float prod = o * Wf2[t];
#pragma unroll
    for (int off = 32; off > 0; off >>= 1) prod += __shfl_down(prod, off);
    if (t == 0) out[g] = prod + bf2[0];
}

extern "C" void kernel_launch(void* const* d_in, const int* in_sizes, int n_in,
                              void* d_out, int out_size, void* d_ws, size_t ws_size,
                              hipStream_t stream)
{
    const float* x     = (const float*)d_in[0];
    const float* ea    = (const float*)d_in[1];
    const int*   eidx  = (const int*)d_in[2];
    const int*   batch = (const int*)d_in[3];
    const float* We1 = (const float*)d_in[4];  const float* be1 = (const float*)d_in[5];
    const float* W11 = (const float*)d_in[6];  const float* b11 = (const float*)d_in[7];
    const float* W12 = (const float*)d_in[8];  const float* b12 = (const float*)d_in[9];
    const float* g1  = (const float*)d_in[10]; const float* bt1 = (const float*)d_in[11];
    const float* We2 = (const float*)d_in[12]; const float* be2 = (const float*)d_in[13];
    const float* W21 = (const float*)d_in[14]; const float* b21 = (const float*)d_in[15];
    const float* W22 = (const float*)d_in[16]; const float* b22 = (const float*)d_in[17];
    const float* g2  = (const float*)d_in[18]; const float* bt2 = (const float*)d_in[19];
    const float* We3 = (const float*)d_in[20]; const float* be3 = (const float*)d_in[21];
    const float* W31 = (const float*)d_in[22]; const float* b31 = (const float*)d_in[23];
    const float* W32 = (const float*)d_in[24]; const float* b32 = (const float*)d_in[25];
    const float* g3  = (const float*)d_in[26]; const float* bt3 = (const float*)d_in[27];
    const float* Wf1 = (const float*)d_in[28]; const float* bf1 = (const float*)d_in[29];
    const float* Wf2 = (const float*)d_in[30]; const float* bf2 = (const float*)d_in[31];

    const int N = in_sizes[0] / 7;
    const int E = in_sizes[1] / 3;
    const int G = out_size;
    const int* src = eidx;
    const int* dst = eidx + E;

    float* ws = (float*)d_ws;
    float* buf_h   = ws;                          // N*128
    float* buf_agg = buf_h + (size_t)N * HID;     // N*128
    float* buf_t   = buf_agg + (size_t)N * HID;   // N*128
    float* bnsums  = buf_t + (size_t)N * HID;     // 256
    float* bnab    = bnsums + 256;                // 256
    float* pools   = bnab + 256;                  // G*128
    float* cntp    = pools + (size_t)G * HID;     // G
    float4* epack  = (float4*)(cntp + G);         // E float4
    unsigned short* h16 = (unsigned short*)(epack + E);  // N*128 bf16
    int*   icnt    = (int*)(h16 + (size_t)N * HID); // N
    int*   ioffs   = icnt + N;                    // N+1
    int*   icur    = ioffs + N + 1;               // N
    int*   ipart   = icur + N;                    // 256
    int*   iexcl   = ipart + 256;                 // N
    unsigned short* wt = (unsigned short*)(iexcl + N);  // 5 x 2 x 16384
    unsigned short* w12h = wt;            unsigned short* w12l = wt + 16384;
    unsigned short* w21h = wt + 32768;    unsigned short* w21l = wt + 49152;
    unsigned short* w22h = wt + 65536;    unsigned short* w22l = wt + 81920;
    unsigned short* w31h = wt + 98304;    unsigned short* w31l = wt + 114688;
    unsigned short* w32h = wt + 131072;   unsigned short* w32l = wt + 147456;

    const long long NH = (long long)N * HID;
    const int blk = 256;
    const unsigned grid_nh2  = (unsigned)((NH / 2 + blk - 1) / blk);
    const unsigned grid_nh   = (unsigned)((NH + blk - 1) / blk);
    const unsigned grid_mfma = (unsigned)((N + 63) / 64);
    const unsigned grid_E    = (unsigned)((E + blk - 1) / blk);
    const unsigned nb_scan   = (unsigned)((N + 255) / 256);
    const unsigned grid_gather = (unsigned)((N + 3) / 4);
    const unsigned grid_gat7 = (unsigned)(((long long)N * 8 + blk - 1) / blk);

    // ---------- W splits (once) ----------
    wsplit<<<64, 256, 0, stream>>>(W12, w12h, w12l);
    wsplit<<<64, 256, 0, stream>>>(W21, w21h, w21l);
    wsplit<<<64, 256, 0, stream>>>(W22, w22h, w22l);
    wsplit<<<64, 256, 0, stream>>>(W31, w31h, w31l);
    wsplit<<<64, 256, 0, stream>>>(W32, w32h, w32l);

    // ---------- build CSR with packed edges ----------
    hipMemsetAsync(icnt, 0, (size_t)N * sizeof(int), stream);
    hist_kernel<<<grid_E, blk, 0, stream>>>(dst, icnt, E);
    scan_block<<<nb_scan, 256, 0, stream>>>(icnt, iexcl, ipart, N);
    scan_partials<<<1, 256, 0, stream>>>(ipart, nb_scan, ioffs, N, E);
    scan_add<<<nb_scan, 256, 0, stream>>>(iexcl, ipart, ioffs, icur, N);
    fill_kernel<<<grid_E, blk, 0, stream>>>(dst, src, ea, icur, epack, E);

    // ---------- layer 1 ----------
    hipMemsetAsync(bnsums, 0, 256 * sizeof(float), stream);
    gather_d7<<<grid_gat7, blk, 0, stream>>>(x, epack, ioffs, We1, be1, buf_agg, N);
    mlp1_fused<false, true><<<grid_mfma, 256, 0, stream>>>(x, buf_agg, W11, b11, w12h, w12l, b12, buf_t, bnsums, N);
    bn_finalize<<<1, 128, 0, stream>>>(bnsums, g1, bt1, bnab, N);
    bn_apply_relu<true><<<grid_nh2, blk, 0, stream>>>(buf_t, bnab, buf_h, h16, NH);

    // ---------- layer 2 ----------
    hipMemsetAsync(bnsums, 0, 256 * sizeof(float), stream);
    gather_d128<<<grid_gather, 256, 0, stream>>>(h16, epack, ioffs, We2, be2, buf_h, buf_agg, N);
    mlp128_fused<false, true><<<grid_mfma, 256, 0, stream>>>(buf_agg, w21h, w21l, b21, w22h, w22l, b22, buf_t, bnsums, N);
    bn_finalize<<<1, 128, 0, stream>>>(bnsums, g2, bt2, bnab, N);
    bn_apply_relu<true><<<grid_nh2, blk, 0, stream>>>(buf_t, bnab, buf_h, h16, NH);

    // ---------- layer 3 ----------
    hipMemsetAsync(bnsums, 0, 256 * sizeof(float), stream);
    gather_d128<<<grid_gather, 256, 0, stream>>>(h16, epack, ioffs, We3, be3, buf_h, buf_agg, N);
    mlp128_fused<false, true><<<grid_mfma, 256, 0, stream>>>(buf_agg, w31h, w31l, b31, w32h, w32l, b32, buf_t, bnsums, N);
    bn_finalize<<<1, 128, 0, stream>>>(bnsums, g3, bt3, bnab, N);

    // ---------- fused BN-apply + pool, then head ----------
    hipMemsetAsync(pools, 0, ((size_t)G * HID + G) * sizeof(float), stream);
    bn_pool<<<grid_nh, blk, 0, stream>>>(buf_t, bnab, batch, pools, cntp, N);
    head_kernel<<<G, 64, 0, stream>>>(pools, cntp, Wf1, bf1, Wf2, bf2, (float*)d_out, G);
}

// Round 11
// 536.020 us; speedup vs baseline: 1.5355x; 1.1850x over previous
//
#include <hip/hip_runtime.h>

#define HID 128

typedef __attribute__((ext_vector_type(8))) short bf16x8;
typedef __attribute__((ext_vector_type(4))) float f32x4;

__device__ inline unsigned short f2bf(float f) {
    unsigned u = __float_as_uint(f);
    unsigned r = (u + 0x7fff + ((u >> 16) & 1)) >> 16;
    return (unsigned short)r;
}
__device__ inline float bf2f(unsigned short b) {
    return __uint_as_float(((unsigned)b) << 16);
}
// split v into trunc-bf16 hi (low 16 bits) + trunc-bf16 lo (high 16 bits)
__device__ inline unsigned packhl(float v) {
    unsigned h = __float_as_uint(v) >> 16;
    float lo = v - __uint_as_float(h << 16);
    unsigned l = __float_as_uint(lo) >> 16;
    return h | (l << 16);
}

// ================= CSR build =================
__global__ void hist_kernel(const int* __restrict__ dst, int* __restrict__ cnt, int E)
{
    int e = blockIdx.x * blockDim.x + threadIdx.x;
    if (e < E) atomicAdd(&cnt[dst[e]], 1);
}

__global__ void scan_block(const int* __restrict__ cnt, int* __restrict__ excl,
                           int* __restrict__ partials, int Nn)
{
    __shared__ int ls[256];
    int i = blockIdx.x * 256 + threadIdx.x;
    int v = (i < Nn) ? cnt[i] : 0;
    ls[threadIdx.x] = v;
    __syncthreads();
    for (int off = 1; off < 256; off <<= 1) {
        int t = (threadIdx.x >= off) ? ls[threadIdx.x - off] : 0;
        __syncthreads();
        ls[threadIdx.x] += t;
        __syncthreads();
    }
    if (i < Nn) excl[i] = ls[threadIdx.x] - v;
    if (threadIdx.x == 255) partials[blockIdx.x] = ls[255];
}

__global__ void scan_partials(int* __restrict__ partials, int nb, int* __restrict__ offsets,
                              int Nn, int E)
{
    __shared__ int ls[256];
    int t = threadIdx.x;
    int v = (t < nb) ? partials[t] : 0;
    ls[t] = v;
    __syncthreads();
    for (int off = 1; off < 256; off <<= 1) {
        int x = (t >= off) ? ls[t - off] : 0;
        __syncthreads();
        ls[t] += x;
        __syncthreads();
    }
    if (t < nb) partials[t] = ls[t] - v;
    if (t == 0) offsets[Nn] = E;
}

__global__ void scan_add(const int* __restrict__ excl, const int* __restrict__ partials,
                         int* __restrict__ offsets, int* __restrict__ cursor, int Nn)
{
    int i = blockIdx.x * 256 + threadIdx.x;
    if (i < Nn) {
        int o = excl[i] + partials[blockIdx.x];
        offsets[i] = o;
        cursor[i] = o;
    }
}

__global__ void fill_kernel(const int* __restrict__ dst, const int* __restrict__ src,
                            const float* __restrict__ ea, int* __restrict__ cursor,
                            float4* __restrict__ epack, int E)
{
    int e = blockIdx.x * blockDim.x + threadIdx.x;
    if (e < E) {
        int pos = atomicAdd(&cursor[dst[e]], 1);
        float4 p;
        p.x = __int_as_float(src[e]);
        p.y = ea[e * 3];
        p.z = ea[e * 3 + 1];
        p.w = ea[e * 3 + 2];
        epack[pos] = p;
    }
}

// ======= W precompute: transpose + hi/lo bf16 split: Wt[n][k] from W[k][n] =======
__global__ void wsplit(const float* __restrict__ W, unsigned short* __restrict__ wh,
                       unsigned short* __restrict__ wl)
{
    int idx = blockIdx.x * 256 + threadIdx.x;
    int n = idx >> 7, k = idx & 127;
    float w = W[k * 128 + n];
    unsigned short h = (unsigned short)(__float_as_uint(w) >> 16);
    float lo = w - bf2f(h);
    unsigned short l = (unsigned short)(__float_as_uint(lo) >> 16);
    wh[idx] = h;
    wl[idx] = l;
}

// ================= layer 1: CSR gather (dim 7) =================
__global__ void gather_d7(const float* __restrict__ x, const float4* __restrict__ epack,
                          const int* __restrict__ offsets,
                          const float* __restrict__ We, const float* __restrict__ be,
                          float* __restrict__ agg, int Nn)
{
    int tid = blockIdx.x * blockDim.x + threadIdx.x;
    int node = tid >> 3;
    int c = tid & 7;
    if (node >= Nn) return;
    float w0 = 0.f, w1 = 0.f, w2 = 0.f, b = 0.f;
    if (c < 7) { w0 = We[c]; w1 = We[7 + c]; w2 = We[14 + c]; b = be[c]; }
    int beg = offsets[node], end = offsets[node + 1];
    float acc = 0.f;
    for (int i = beg; i < end; ++i) {
        float4 ep = epack[i];
        int s = __float_as_int(ep.x);
        float v = b;
        v = fmaf(ep.y, w0, v);
        v = fmaf(ep.z, w1, v);
        v = fmaf(ep.w, w2, v);
        if (c < 7) v += x[s * 7 + c];
        acc += fmaxf(v, 0.f);
    }
    if (c < 7) agg[node * 7 + c] = acc;
}

// ================= layers 2/3: gather, 4x unrolled, writes h+agg =================
__global__ void gather_d128(const unsigned short* __restrict__ h16,
                            const float4* __restrict__ epack,
                            const int* __restrict__ offsets,
                            const float* __restrict__ We, const float* __restrict__ be,
                            const float* __restrict__ hprev,
                            float* __restrict__ agg, int Nn)
{
    int node = blockIdx.x * (blockDim.x >> 6) + (threadIdx.x >> 6);
    if (node >= Nn) return;
    int lane = threadIdx.x & 63;
    int beg = offsets[node], end = offsets[node + 1];
    const float2* W2 = (const float2*)We;
    float2 w0 = W2[lane];
    float2 w1 = W2[64 + lane];
    float2 w2 = W2[128 + lane];
    float2 bb = ((const float2*)be)[lane];
    float accx = 0.f, accy = 0.f;

    int i = beg;
    for (; i + 4 <= end; i += 4) {
        float4 e0 = epack[i], e1 = epack[i + 1], e2 = epack[i + 2], e3 = epack[i + 3];
        ushort2 p0 = ((const ushort2*)(h16 + (size_t)__float_as_int(e0.x) * HID))[lane];
        ushort2 p1 = ((const ushort2*)(h16 + (size_t)__float_as_int(e1.x) * HID))[lane];
        ushort2 p2 = ((const ushort2*)(h16 + (size_t)__float_as_int(e2.x) * HID))[lane];
        ushort2 p3 = ((const ushort2*)(h16 + (size_t)__float_as_int(e3.x) * HID))[lane];
        float vx, vy;
        vx = bb.x + bf2f(p0.x);
        vx = fmaf(e0.y, w0.x, vx); vx = fmaf(e0.z, w1.x, vx); vx = fmaf(e0.w, w2.x, vx);
        vy = bb.y + bf2f(p0.y);
        vy = fmaf(e0.y, w0.y, vy); vy = fmaf(e0.z, w1.y, vy); vy = fmaf(e0.w, w2.y, vy);
        accx += fmaxf(vx, 0.f); accy += fmaxf(vy, 0.f);
        vx = bb.x + bf2f(p1.x);
        vx = fmaf(e1.y, w0.x, vx); vx = fmaf(e1.z, w1.x, vx); vx = fmaf(e1.w, w2.x, vx);
        vy = bb.y + bf2f(p1.y);
        vy = fmaf(e1.y, w0.y, vy); vy = fmaf(e1.z, w1.y, vy); vy = fmaf(e1.w, w2.y, vy);
        accx += fmaxf(vx, 0.f); accy += fmaxf(vy, 0.f);
        vx = bb.x + bf2f(p2.x);
        vx = fmaf(e2.y, w0.x, vx); vx = fmaf(e2.z, w1.x, vx); vx = fmaf(e2.w, w2.x, vx);
        vy = bb.y + bf2f(p2.y);
        vy = fmaf(e2.y, w0.y, vy); vy = fmaf(e2.z, w1.y, vy); vy = fmaf(e2.w, w2.y, vy);
        accx += fmaxf(vx, 0.f); accy += fmaxf(vy, 0.f);
        vx = bb.x + bf2f(p3.x);
        vx = fmaf(e3.y, w0.x, vx); vx = fmaf(e3.z, w1.x, vx); vx = fmaf(e3.w, w2.x, vx);
        vy = bb.y + bf2f(p3.y);
        vy = fmaf(e3.y, w0.y, vy); vy = fmaf(e3.z, w1.y, vy); vy = fmaf(e3.w, w2.y, vy);
        accx += fmaxf(vx, 0.f); accy += fmaxf(vy, 0.f);
    }
    for (; i < end; ++i) {
        float4 ep = epack[i];
        ushort2 hp = ((const ushort2*)(h16 + (size_t)__float_as_int(ep.x) * HID))[lane];
        float vx = bb.x + bf2f(hp.x);
        vx = fmaf(ep.y, w0.x, vx); vx = fmaf(ep.z, w1.x, vx); vx = fmaf(ep.w, w2.x, vx);
        float vy = bb.y + bf2f(hp.y);
        vy = fmaf(ep.y, w0.y, vy); vy = fmaf(ep.z, w1.y, vy); vy = fmaf(ep.w, w2.y, vy);
        accx += fmaxf(vx, 0.f);
        accy += fmaxf(vy, 0.f);
    }
    float2 hv = ((const float2*)(hprev + (size_t)node * HID))[lane];
    float2 outv = {accx + hv.x, accy + hv.y};
    ((float2*)(agg + (size_t)node * HID))[lane] = outv;
}

// ===== MFMA core: acc[2][4] = T(64 rows packed hi/lo) @ Wt for this wave's 32 cols =====
// wave w owns cols [32w, 32w+32): C-tiles ctg0=2w, ctg1=2w+1; 4 row-frags of 16.
__device__ __forceinline__ void mfma_core(
    const unsigned* T,
    const unsigned short* __restrict__ Wh, const unsigned short* __restrict__ Wl,
    const float* __restrict__ bias,
    int wave, int q, int li, f32x4 (&acc)[2][4])
{
    int ctg0 = wave * 2, ctg1 = wave * 2 + 1;
    float b0 = bias[ctg0 * 16 + li];
    float b1v = bias[ctg1 * 16 + li];
#pragma unroll
    for (int rf = 0; rf < 4; ++rf) {
        acc[0][rf][0] = b0;  acc[0][rf][1] = b0;  acc[0][rf][2] = b0;  acc[0][rf][3] = b0;
        acc[1][rf][0] = b1v; acc[1][rf][1] = b1v; acc[1][rf][2] = b1v; acc[1][rf][3] = b1v;
    }
#pragma unroll
    for (int kb = 0; kb < 4; ++kb) {
        int k0 = kb * 32 + q * 8;
        size_t w0off = (size_t)(ctg0 * 16 + li) * HID + k0;
        size_t w1off = (size_t)(ctg1 * 16 + li) * HID + k0;
        bf16x8 bh0 = *(const bf16x8*)(Wh + w0off);
        bf16x8 bl0 = *(const bf16x8*)(Wl + w0off);
        bf16x8 bh1 = *(const bf16x8*)(Wh + w1off);
        bf16x8 bl1 = *(const bf16x8*)(Wl + w1off);
#pragma unroll
        for (int rf = 0; rf < 4; ++rf) {
            const unsigned* Tp = T + (rf * 16 + li) * 132 + k0;
            uint4 pa = *(const uint4*)Tp;
            uint4 pb = *(const uint4*)(Tp + 4);
            unsigned pv[8] = {pa.x, pa.y, pa.z, pa.w, pb.x, pb.y, pb.z, pb.w};
            bf16x8 ah, al;
#pragma unroll
            for (int j = 0; j < 8; ++j) {
                ah[j] = (short)(pv[j] & 0xffffu);
                al[j] = (short)(pv[j] >> 16);
            }
            acc[0][rf] = __builtin_amdgcn_mfma_f32_16x16x32_bf16(ah, bh0, acc[0][rf], 0, 0, 0);
            acc[0][rf] = __builtin_amdgcn_mfma_f32_16x16x32_bf16(ah, bl0, acc[0][rf], 0, 0, 0);
            acc[0][rf] = __builtin_amdgcn_mfma_f32_16x16x32_bf16(al, bh0, acc[0][rf], 0, 0, 0);
            acc[1][rf] = __builtin_amdgcn_mfma_f32_16x16x32_bf16(ah, bh1, acc[1][rf], 0, 0, 0);
            acc[1][rf] = __builtin_amdgcn_mfma_f32_16x16x32_bf16(ah, bl1, acc[1][rf], 0, 0, 0);
            acc[1][rf] = __builtin_amdgcn_mfma_f32_16x16x32_bf16(al, bh1, acc[1][rf], 0, 0, 0);
        }
    }
}

// global epilogue: write C (+optional relu, +optional BN stats via wave-owned cols)
template <bool RELU, bool STATS>
__device__ __forceinline__ void epilogue_global(
    f32x4 (&acc)[2][4], float* __restrict__ C, float* __restrict__ bnsums,
    float* sls, float* slq, int node0, int wave, int q, int li, int t, int N)
{
#pragma unroll
    for (int ct = 0; ct < 2; ++ct) {
        int colb = (wave * 2 + ct) * 16 + li;
        float sv = 0.f, qv = 0.f;
#pragma unroll
        for (int rf = 0; rf < 4; ++rf) {
#pragma unroll
            for (int r = 0; r < 4; ++r) {
                int n = node0 + rf * 16 + q * 4 + r;
                float v = acc[ct][rf][r];
                if (RELU) v = fmaxf(v, 0.f);
                if (n < N) {
                    C[(size_t)n * HID + colb] = v;
                    if (STATS) { sv += v; qv = fmaf(v, v, qv); }
                }
            }
        }
        if (STATS) {
            sv += __shfl_down(sv, 16); sv += __shfl_down(sv, 32);
            qv += __shfl_down(qv, 16); qv += __shfl_down(qv, 32);
            if (q == 0) { sls[colb] = sv; slq[colb] = qv; }   // unique owner per col
        }
    }
    if (STATS) {
        __syncthreads();
        if (t < 128) {
            atomicAdd(&bnsums[t], sls[t]);
            atomicAdd(&bnsums[128 + t], slq[t]);
        }
    }
}

// ===== fused MLP layers 2/3: C = Lin2(relu(Lin1(A))), BN stats fused =====
template <bool RELU, bool STATS>
__global__ __launch_bounds__(256) void mlp128_fused(
    const float* __restrict__ A,
    const unsigned short* __restrict__ W1h, const unsigned short* __restrict__ W1l,
    const float* __restrict__ b1,
    const unsigned short* __restrict__ W2h, const unsigned short* __restrict__ W2l,
    const float* __restrict__ b2,
    float* __restrict__ C, float* __restrict__ bnsums, int N)
{
    __shared__ unsigned Ta[64 * 132];
    __shared__ unsigned Tb[64 * 132];
    __shared__ float sls[128], slq[128];
    int t = threadIdx.x;
    int wave = t >> 6, lane = t & 63;
    int q = lane >> 4, li = lane & 15;
    int node0 = blockIdx.x * 64;

    // ---- stage A (fp32 global -> packed hi/lo LDS), coalesced, once per block ----
    {
        const float4* A4 = (const float4*)(A + (size_t)node0 * HID);
        int rows = N - node0 < 64 ? (N - node0) : 64;
        int limit4 = 32 * rows;
#pragma unroll
        for (int i = 0; i < 8; ++i) {
            int idx = t + i * 256;
            float4 v = {0.f, 0.f, 0.f, 0.f};
            if (idx < limit4) v = A4[idx];
            int row = idx >> 5, c4 = idx & 31;
            uint4 pk;
            pk.x = packhl(v.x); pk.y = packhl(v.y);
            pk.z = packhl(v.z); pk.w = packhl(v.w);
            *(uint4*)(Ta + row * 132 + c4 * 4) = pk;
        }
    }
    __syncthreads();

    // ---- phase 1: Ta @ W1 -> relu -> packed Tb ----
    {
        f32x4 acc[2][4];
        mfma_core(Ta, W1h, W1l, b1, wave, q, li, acc);
#pragma unroll
        for (int ct = 0; ct < 2; ++ct) {
            int colb = (wave * 2 + ct) * 16 + li;
#pragma unroll
            for (int rf = 0; rf < 4; ++rf) {
#pragma unroll
                for (int r = 0; r < 4; ++r) {
                    float v = fmaxf(acc[ct][rf][r], 0.f);
                    Tb[(rf * 16 + q * 4 + r) * 132 + colb] = packhl(v);
                }
            }
        }
    }
    __syncthreads();

    // ---- phase 2: Tb @ W2 -> C (+stats) ----
    {
        f32x4 acc[2][4];
        mfma_core(Tb, W2h, W2l, b2, wave, q, li, acc);
        epilogue_global<RELU, STATS>(acc, C, bnsums, sls, slq, node0, wave, q, li, t, N);
    }
}

// ===== fused MLP layer 1: phase-1 K=7 fp32 vector -> packed Tb, phase-2 MFMA =====
template <bool RELU, bool STATS>
__global__ __launch_bounds__(256) void mlp1_fused(
    const float* __restrict__ x, const float* __restrict__ agg,
    const float* __restrict__ W1, const float* __restrict__ b1,     // [7][128]
    const unsigned short* __restrict__ W2h, const unsigned short* __restrict__ W2l,
    const float* __restrict__ b2,
    float* __restrict__ C, float* __restrict__ bnsums, int N)
{
    __shared__ unsigned Tb[64 * 132];
    __shared__ float sls[128], slq[128];
    int t = threadIdx.x;
    int wave = t >> 6, lane = t & 63;
    int q = lane >> 4, li = lane & 15;
    int node0 = blockIdx.x * 64;

    // phase 1: rows wave*16+li (4 waves cover 64 rows), q covers col-groups of 32
    {
        int row = node0 + wave * 16 + li;
        bool ok = row < N;
        float xa[7];
#pragma unroll
        for (int k = 0; k < 7; ++k) xa[k] = ok ? (x[row * 7 + k] + agg[row * 7 + k]) : 0.f;
        const float4* W14 = (const float4*)W1;
        const float4* b14 = (const float4*)b1;
        unsigned* Trow = Tb + (wave * 16 + li) * 132 + q * 32;
#pragma unroll
        for (int c4 = 0; c4 < 8; ++c4) {
            float4 v = b14[q * 8 + c4];
#pragma unroll
            for (int k = 0; k < 7; ++k) {
                float4 w = W14[k * 32 + q * 8 + c4];
                v.x = fmaf(xa[k], w.x, v.x);
                v.y = fmaf(xa[k], w.y, v.y);
                v.z = fmaf(xa[k], w.z, v.z);
                v.w = fmaf(xa[k], w.w, v.w);
            }
            uint4 pk;
            pk.x = packhl(fmaxf(v.x, 0.f));
            pk.y = packhl(fmaxf(v.y, 0.f));
            pk.z = packhl(fmaxf(v.z, 0.f));
            pk.w = packhl(fmaxf(v.w, 0.f));
            *(uint4*)(Trow + c4 * 4) = pk;
        }
    }
    __syncthreads();

    // phase 2
    {
        f32x4 acc[2][4];
        mfma_core(Tb, W2h, W2l, b2, wave, q, li, acc);
        epilogue_global<RELU, STATS>(acc, C, bnsums, sls, slq, node0, wave, q, li, t, N);
    }
}

// ================= BN =================
__global__ void bn_finalize(const float* __restrict__ sums, const float* __restrict__ g,
                            const float* __restrict__ bt, float* __restrict__ ab, int N)
{
    int c = threadIdx.x;
    if (c < 128) {
        float inv = 1.f / (float)N;
        float mu = sums[c] * inv;
        float var = sums[128 + c] * inv - mu * mu;
        float rs = rsqrtf(fmaxf(var, 0.f) + 1e-5f);
        float a = g[c] * rs;
        ab[c] = a;
        ab[128 + c] = bt[c] - a * mu;
    }
}

template <bool W16>
__global__ void bn_apply_relu(const float* __restrict__ h, const float* __restrict__ ab,
                              float* __restrict__ out, unsigned short* __restrict__ h16,
                              long long total)
{
    long long i = ((long long)blockIdx.x * blockDim.x + threadIdx.x) * 2;
    if (i >= total) return;
    int c = (int)(i & 127);
    float2 hv = *(const float2*)(h + i);
    float v0 = fmaxf(fmaf(hv.x, ab[c], ab[128 + c]), 0.f);
    float v1 = fmaxf(fmaf(hv.y, ab[c + 1], ab[129 + c]), 0.f);
    float2 ov = {v0, v1};
    *(float2*)(out + i) = ov;
    if (W16) {
        unsigned pair = (unsigned)f2bf(v0) | ((unsigned)f2bf(v1) << 16);
        *(unsigned*)(h16 + i) = pair;
    }
}

// ================= fused layer-3 BN-apply + mean-pool scatter =================
__global__ void bn_pool(const float* __restrict__ agg, const float* __restrict__ ab,
                        const int* __restrict__ batch,
                        float* __restrict__ pools, float* __restrict__ cnt, int N)
{
    long long i = (long long)blockIdx.x * blockDim.x + threadIdx.x;
    long long total = (long long)N * HID;
    if (i >= total) return;
    int n = (int)(i >> 7);
    int c = (int)(i & 127);
    int g = batch[n];
    float v = fmaxf(fmaf(agg[i], ab[c], ab[128 + c]), 0.f);
    atomicAdd(&pools[(long long)g * HID + c], v);
    if (c == 0) atomicAdd(&cnt[g], 1.f);
}

__global__ void head_kernel(const float* __restrict__ pools, const float* __restrict__ cnt,
                            const float* __restrict__ Wf1, const float* __restrict__ bf1,
                            const float* __restrict__ Wf2, const float* __restrict__ bf2,
                            float* __restrict__ out, int G)
{
    int g = blockIdx.x;
    int t = threadIdx.x;
    __shared__ float p[128];
    float inv = 1.f / fmaxf(cnt[g], 1.f);
    p[t] = pools[g * 128 + t] * inv;
    p[t + 64] = pools[g * 128 + t + 64] * inv;
    __syncthreads();
    float o = bf1[t];
#pragma unroll 8
    for (int k = 0; k < 128; ++k) o = fmaf(p[k], Wf1[k * 64 + t], o);
    o = fmaxf(o, 0.f);
    float prod = o * Wf2[t];
#pragma unroll
    for (int off = 32; off > 0; off >>= 1) prod += __shfl_down(prod, off);
    if (t == 0) out[g] = prod + bf2[0];
}

extern "C" void kernel_launch(void* const* d_in, const int* in_sizes, int n_in,
                              void* d_out, int out_size, void* d_ws, size_t ws_size,
                              hipStream_t stream)
{
    const float* x     = (const float*)d_in[0];
    const float* ea    = (const float*)d_in[1];
    const int*   eidx  = (const int*)d_in[2];
    const int*   batch = (const int*)d_in[3];
    const float* We1 = (const float*)d_in[4];  const float* be1 = (const float*)d_in[5];
    const float* W11 = (const float*)d_in[6];  const float* b11 = (const float*)d_in[7];
    const float* W12 = (const float*)d_in[8];  const float* b12 = (const float*)d_in[9];
    const float* g1  = (const float*)d_in[10]; const float* bt1 = (const float*)d_in[11];
    const float* We2 = (const float*)d_in[12]; const float* be2 = (const float*)d_in[13];
    const float* W21 = (const float*)d_in[14]; const float* b21 = (const float*)d_in[15];
    const float* W22 = (const float*)d_in[16]; const float* b22 = (const float*)d_in[17];
    const float* g2  = (const float*)d_in[18]; const float* bt2 = (const float*)d_in[19];
    const float* We3 = (const float*)d_in[20]; const float* be3 = (const float*)d_in[21];
    const float* W31 = (const float*)d_in[22]; const float* b31 = (const float*)d_in[23];
    const float* W32 = (const float*)d_in[24]; const float* b32 = (const float*)d_in[25];
    const float* g3  = (const float*)d_in[26]; const float* bt3 = (const float*)d_in[27];
    const float* Wf1 = (const float*)d_in[28]; const float* bf1 = (const float*)d_in[29];
    const float* Wf2 = (const float*)d_in[30]; const float* bf2 = (const float*)d_in[31];

    const int N = in_sizes[0] / 7;
    const int E = in_sizes[1] / 3;
    const int G = out_size;
    const int* src = eidx;
    const int* dst = eidx + E;

    float* ws = (float*)d_ws;
    float* buf_h   = ws;                          // N*128
    float* buf_agg = buf_h + (size_t)N * HID;     // N*128
    float* buf_t   = buf_agg + (size_t)N * HID;   // N*128
    float* bnsums  = buf_t + (size_t)N * HID;     // 256
    float* bnab    = bnsums + 256;                // 256
    float* pools   = bnab + 256;                  // G*128
    float* cntp    = pools + (size_t)G * HID;     // G
    float4* epack  = (float4*)(cntp + G);         // E float4
    unsigned short* h16 = (unsigned short*)(epack + E);  // N*128 bf16
    int*   icnt    = (int*)(h16 + (size_t)N * HID); // N
    int*   ioffs   = icnt + N;                    // N+1
    int*   icur    = ioffs + N + 1;               // N
    int*   ipart   = icur + N;                    // 256
    int*   iexcl   = ipart + 256;                 // N
    unsigned short* wt = (unsigned short*)(iexcl + N);  // 5 x 2 x 16384
    unsigned short* w12h = wt;            unsigned short* w12l = wt + 16384;
    unsigned short* w21h = wt + 32768;    unsigned short* w21l = wt + 49152;
    unsigned short* w22h = wt + 65536;    unsigned short* w22l = wt + 81920;
    unsigned short* w31h = wt + 98304;    unsigned short* w31l = wt + 114688;
    unsigned short* w32h = wt + 131072;   unsigned short* w32l = wt + 147456;

    const long long NH = (long long)N * HID;
    const int blk = 256;
    const unsigned grid_nh2  = (unsigned)((NH / 2 + blk - 1) / blk);
    const unsigned grid_nh   = (unsigned)((NH + blk - 1) / blk);
    const unsigned grid_mfma = (unsigned)((N + 63) / 64);
    const unsigned grid_E    = (unsigned)((E + blk - 1) / blk);
    const unsigned nb_scan   = (unsigned)((N + 255) / 256);
    const unsigned grid_gather = (unsigned)((N + 3) / 4);
    const unsigned grid_gat7 = (unsigned)(((long long)N * 8 + blk - 1) / blk);

    // ---------- W splits (once) ----------
    wsplit<<<64, 256, 0, stream>>>(W12, w12h, w12l);
    wsplit<<<64, 256, 0, stream>>>(W21, w21h, w21l);
    wsplit<<<64, 256, 0, stream>>>(W22, w22h, w22l);
    wsplit<<<64, 256, 0, stream>>>(W31, w31h, w31l);
    wsplit<<<64, 256, 0, stream>>>(W32, w32h, w32l);

    // ---------- build CSR with packed edges ----------
    hipMemsetAsync(icnt, 0, (size_t)N * sizeof(int), stream);
    hist_kernel<<<grid_E, blk, 0, stream>>>(dst, icnt, E);
    scan_block<<<nb_scan, 256, 0, stream>>>(icnt, iexcl, ipart, N);
    scan_partials<<<1, 256, 0, stream>>>(ipart, nb_scan, ioffs, N, E);
    scan_add<<<nb_scan, 256, 0, stream>>>(iexcl, ipart, ioffs, icur, N);
    fill_kernel<<<grid_E, blk, 0, stream>>>(dst, src, ea, icur, epack, E);

    // ---------- layer 1 ----------
    hipMemsetAsync(bnsums, 0, 256 * sizeof(float), stream);
    gather_d7<<<grid_gat7, blk, 0, stream>>>(x, epack, ioffs, We1, be1, buf_agg, N);
    mlp1_fused<false, true><<<grid_mfma, 256, 0, stream>>>(x, buf_agg, W11, b11, w12h, w12l, b12, buf_t, bnsums, N);
    bn_finalize<<<1, 128, 0, stream>>>(bnsums, g1, bt1, bnab, N);
    bn_apply_relu<true><<<grid_nh2, blk, 0, stream>>>(buf_t, bnab, buf_h, h16, NH);

    // ---------- layer 2 ----------
    hipMemsetAsync(bnsums, 0, 256 * sizeof(float), stream);
    gather_d128<<<grid_gather, 256, 0, stream>>>(h16, epack, ioffs, We2, be2, buf_h, buf_agg, N);
    mlp128_fused<false, true><<<grid_mfma, 256, 0, stream>>>(buf_agg, w21h, w21l, b21, w22h, w22l, b22, buf_t, bnsums, N);
    bn_finalize<<<1, 128, 0, stream>>>(bnsums, g2, bt2, bnab, N);
    bn_apply_relu<true><<<grid_nh2, blk, 0, stream>>>(buf_t, bnab, buf_h, h16, NH);

    // ---------- layer 3 ----------
    hipMemsetAsync(bnsums, 0, 256 * sizeof(float), stream);
    gather_d128<<<grid_gather, 256, 0, stream>>>(h16, epack, ioffs, We3, be3, buf_h, buf_agg, N);
    mlp128_fused<false, true><<<grid_mfma, 256, 0, stream>>>(buf_agg, w31h, w31l, b31, w32h, w32l, b32, buf_t, bnsums, N);
    bn_finalize<<<1, 128, 0, stream>>>(bnsums, g3, bt3, bnab, N);

    // ---------- fused BN-apply + pool, then head ----------
    hipMemsetAsync(pools, 0, ((size_t)G * HID + G) * sizeof(float), stream);
    bn_pool<<<grid_nh, blk, 0, stream>>>(buf_t, bnab, batch, pools, cntp, N);
    head_kernel<<<G, 64, 0, stream>>>(pools, cntp, Wf1, bf1, Wf2, bf2, (float*)d_out, G);
}